// Round 1
// baseline (349.558 us; speedup 1.0000x reference)
//
#include <hip/hip_runtime.h>
#include <hip/hip_bf16.h>

typedef __attribute__((ext_vector_type(8))) __bf16 bf16x8;
typedef __attribute__((ext_vector_type(4))) __bf16 bf16x4;
typedef __attribute__((ext_vector_type(4))) float f32x4;

static __device__ __forceinline__ f32x4 mfma_bf16(bf16x8 a, bf16x8 b, f32x4 c) {
  return __builtin_amdgcn_mfma_f32_16x16x32_bf16(a, b, c, 0, 0, 0);
}

// async global->LDS, 16B per lane. LDS dest must be linear in lane order.
static __device__ __forceinline__ void gload_lds16(const void* g, void* l) {
  __builtin_amdgcn_global_load_lds(
      (__attribute__((address_space(1))) unsigned int*)g,
      (__attribute__((address_space(3))) unsigned int*)l, 16, 0, 0);
}

// ---------------------------------------------------------------- fp32 -> bf16
__global__ void cvt_bf16(const float* __restrict__ in, __bf16* __restrict__ out, int n4) {
  int i = blockIdx.x * blockDim.x + threadIdx.x;
  if (i >= n4) return;
  f32x4 v = ((const f32x4*)in)[i];
  bf16x4 o;
#pragma unroll
  for (int k = 0; k < 4; ++k) o[k] = (__bf16)v[k];
  ((bf16x4*)out)[i] = o;
}

// ---------------------------------------------------------------- GEMM  C = A @ W^T
// A: 8192x1024 bf16 row-major, W: 1024x1024 bf16 row-major (we need x @ W.T, so
// both operand fragments are contiguous 8-elem reads along K).
// MODE 0: Q  -> rope + *0.125, bf16 token-major [m][n]
// MODE 1: K  -> rope,          bf16 token-major [m][n]
// MODE 2: V  -> bf16 TRANSPOSED [b*1024 + n][tok]   (i.e. [b,h,d,s])
// MODE 3: OUT-> fp32 [m][n] to d_out
template <int MODE>
__global__ __launch_bounds__(256, 2)
void gemm_bt(const __bf16* __restrict__ A, const __bf16* __restrict__ W,
             void* __restrict__ outp,
             const float* __restrict__ fcos, const float* __restrict__ fsin) {
  constexpr int K = 1024;
  constexpr int NCOL = 1024;
  __shared__ __align__(16) __bf16 Alds[128 * 32];
  __shared__ __align__(16) __bf16 Blds[128 * 32];
  const int t = threadIdx.x;
  const int lane = t & 63;
  const int wave = t >> 6;
  const int g = lane >> 4, ln = lane & 15;
  const int wm = wave >> 1, wn = wave & 1;  // 2x2 waves of 64x64
  const int bm = blockIdx.y, bn = blockIdx.x;

  f32x4 acc[4][4] = {};

  const int srow = t >> 2;         // 0..63
  const int scol = (t & 3) * 8;    // k-offset (elems)
  const __bf16* Ag = A + (size_t)(bm * 128 + srow) * K + scol;
  const __bf16* Wg = W + (size_t)(bn * 128 + srow) * K + scol;
  __bf16* la = Alds + t * 8;       // linear: row*32 + scol
  __bf16* lb = Blds + t * 8;

  for (int k0 = 0; k0 < K; k0 += 32) {
    gload_lds16(Ag + k0, la);
    gload_lds16(Ag + k0 + 64 * K, la + 2048);
    gload_lds16(Wg + k0, lb);
    gload_lds16(Wg + k0 + 64 * K, lb + 2048);
    __syncthreads();
    bf16x8 af[4], bfr[4];
#pragma unroll
    for (int i = 0; i < 4; ++i)
      af[i] = *(const bf16x8*)(Alds + (wm * 64 + i * 16 + ln) * 32 + g * 8);
#pragma unroll
    for (int j = 0; j < 4; ++j)
      bfr[j] = *(const bf16x8*)(Blds + (wn * 64 + j * 16 + ln) * 32 + g * 8);
#pragma unroll
    for (int i = 0; i < 4; ++i)
#pragma unroll
      for (int j = 0; j < 4; ++j)
        acc[i][j] = mfma_bf16(af[i], bfr[j], acc[i][j]);
    __syncthreads();
  }

  // Epilogue. D-layout: col = lane&15 (within 16), row = (lane>>4)*4 + r.
#pragma unroll
  for (int i = 0; i < 4; ++i) {
    const int mbase = bm * 128 + wm * 64 + i * 16 + g * 4;
#pragma unroll
    for (int j = 0; j < 4; ++j) {
      const int col = bn * 128 + wn * 64 + j * 16 + ln;
      if constexpr (MODE == 0 || MODE == 1) {
        const int fi = (col & 63) >> 1;
        const bool odd = (col & 1) != 0;
        __bf16* O = (__bf16*)outp;
#pragma unroll
        for (int r = 0; r < 4; ++r) {
          const int row = mbase + r;
          const int tok = row & 2047;
          const float cs = fcos[tok * 32 + fi];
          const float sn = fsin[tok * 32 + fi];
          const float own = acc[i][j][r];
          const float oth = __shfl_xor(own, 1);  // partner column d^1
          float val = own * cs + (odd ? oth * sn : -oth * sn);
          if constexpr (MODE == 0) val *= 0.125f;  // 1/sqrt(64)
          O[(size_t)row * NCOL + col] = (__bf16)val;
        }
      } else if constexpr (MODE == 2) {
        __bf16* O = (__bf16*)outp;
        const int bb = mbase >> 11;
        const int tok = mbase & 2047;
        bf16x4 pk;
#pragma unroll
        for (int r = 0; r < 4; ++r) pk[r] = (__bf16)acc[i][j][r];
        *(bf16x4*)(O + ((size_t)(bb * 1024 + col)) * 2048 + tok) = pk;
      } else {
        float* O = (float*)outp;
#pragma unroll
        for (int r = 0; r < 4; ++r)
          O[(size_t)(mbase + r) * NCOL + col] = acc[i][j][r];
      }
    }
  }
}

// ---------------------------------------------------------------- flash attention
// Q,K: bf16 token-major [b,s,h*64+d] (Q pre-scaled by 0.125, both rope'd).
// Vt:  bf16 [b*1024 + h*64 + d][s].
// U:   bf16 token-major [b,s,h*64+d].
// Block: 64 q-rows (4 waves x 16), KV tiles of 64, causal.
__global__ __launch_bounds__(256, 2)
void attn_fwd(const __bf16* __restrict__ Q, const __bf16* __restrict__ Kk,
              const __bf16* __restrict__ Vt, __bf16* __restrict__ U) {
  constexpr int S = 2048;
  // K-step regions [2][64][32]: rows are 64B -> conflict-minimal b128 reads.
  __shared__ __align__(16) __bf16 Klds[2 * 64 * 32];
  __shared__ __align__(16) __bf16 Vlds[2 * 64 * 32];
  __shared__ __align__(16) __bf16 Plds[4 * 2 * 16 * 40];  // per-wave, 80B rows

  const int t = threadIdx.x;
  const int lane = t & 63, wave = t >> 6;
  const int g = lane >> 4, ln = lane & 15;
  const int qt = blockIdx.x, bh = blockIdx.y;
  const int b = bh >> 4, h = bh & 15;
  const int q0 = qt * 64;

  // Q fragments in registers: row = lane&15 of this wave's 16 rows, k = s*32+g*8+j
  const __bf16* Qb = Q + ((size_t)(b * S + q0 + wave * 16 + ln)) * 1024 + h * 64;
  const bf16x8 qf0 = *(const bf16x8*)(Qb + g * 8);
  const bf16x8 qf1 = *(const bf16x8*)(Qb + 32 + g * 8);

  f32x4 o[4] = {};
  float mrow[4], lrow[4];
#pragma unroll
  for (int r = 0; r < 4; ++r) { mrow[r] = -3.0e38f; lrow[r] = 0.f; }

  const int srow = t >> 2;        // 0..63
  const int scol = (t & 3) * 8;
  const __bf16* Kg = Kk + ((size_t)(b * S + srow)) * 1024 + h * 64 + scol;
  const __bf16* Vg = Vt + ((size_t)(b * 1024 + h * 64 + srow)) * 2048 + scol;

  for (int kt = 0; kt <= qt; ++kt) {
    const int kv0 = kt * 64;
    gload_lds16(Kg + (size_t)kv0 * 1024,      Klds + t * 8);
    gload_lds16(Kg + (size_t)kv0 * 1024 + 32, Klds + 2048 + t * 8);
    gload_lds16(Vg + kv0,                      Vlds + t * 8);
    gload_lds16(Vg + kv0 + 32,                 Vlds + 2048 + t * 8);
    __syncthreads();

    // S = Q K^T : 16(q) x 64(kv) per wave
    f32x4 sa[4] = {};
#pragma unroll
    for (int s = 0; s < 2; ++s) {
      const bf16x8 qf = s ? qf1 : qf0;
#pragma unroll
      for (int c = 0; c < 4; ++c) {
        bf16x8 kf = *(const bf16x8*)(Klds + s * 2048 + (c * 16 + ln) * 32 + g * 8);
        sa[c] = mfma_bf16(qf, kf, sa[c]);
      }
    }

    if (kt == qt) {  // causal mask on diagonal tile
#pragma unroll
      for (int c = 0; c < 4; ++c) {
        const int colk = c * 16 + ln;
#pragma unroll
        for (int r = 0; r < 4; ++r) {
          const int rowq = wave * 16 + g * 4 + r;
          if (colk > rowq) sa[c][r] = -1e30f;
        }
      }
    }

    // online softmax (rows live on 16-lane groups)
    float pm[4];
#pragma unroll
    for (int r = 0; r < 4; ++r)
      pm[r] = fmaxf(fmaxf(sa[0][r], sa[1][r]), fmaxf(sa[2][r], sa[3][r]));
#pragma unroll
    for (int off = 8; off >= 1; off >>= 1)
#pragma unroll
      for (int r = 0; r < 4; ++r) pm[r] = fmaxf(pm[r], __shfl_xor(pm[r], off));

    float alpha[4], rs[4];
#pragma unroll
    for (int r = 0; r < 4; ++r) {
      const float mn = fmaxf(mrow[r], pm[r]);
      alpha[r] = __expf(mrow[r] - mn);
      mrow[r] = mn;
      rs[r] = 0.f;
    }
#pragma unroll
    for (int c = 0; c < 4; ++c)
#pragma unroll
      for (int r = 0; r < 4; ++r) {
        const float p = __expf(sa[c][r] - mrow[r]);
        rs[r] += p;
        Plds[wave * 1280 + (c >> 1) * 640 + (g * 4 + r) * 40 + (c & 1) * 16 + ln] = (__bf16)p;
      }
#pragma unroll
    for (int off = 8; off >= 1; off >>= 1)
#pragma unroll
      for (int r = 0; r < 4; ++r) rs[r] += __shfl_xor(rs[r], off);
#pragma unroll
    for (int r = 0; r < 4; ++r) lrow[r] = lrow[r] * alpha[r] + rs[r];
#pragma unroll
    for (int c = 0; c < 4; ++c)
#pragma unroll
      for (int r = 0; r < 4; ++r) o[c][r] *= alpha[r];

    // O += P V : A-frag of P from per-wave LDS, B-frag of V from region LDS
#pragma unroll
    for (int s = 0; s < 2; ++s) {
      bf16x8 pa = *(const bf16x8*)(Plds + wave * 1280 + s * 640 + ln * 40 + g * 8);
#pragma unroll
      for (int c = 0; c < 4; ++c) {
        bf16x8 vb = *(const bf16x8*)(Vlds + s * 2048 + (c * 16 + ln) * 32 + g * 8);
        o[c] = mfma_bf16(pa, vb, o[c]);
      }
    }
    __syncthreads();
  }

  // normalize + write U (token-major)
  __bf16* Ub = U + ((size_t)(b * S + q0 + wave * 16 + g * 4)) * 1024 + h * 64;
#pragma unroll
  for (int c = 0; c < 4; ++c)
#pragma unroll
    for (int r = 0; r < 4; ++r)
      Ub[(size_t)r * 1024 + c * 16 + ln] = (__bf16)(o[c][r] / lrow[r]);
}

// ---------------------------------------------------------------- launch
extern "C" void kernel_launch(void* const* d_in, const int* in_sizes, int n_in,
                              void* d_out, int out_size, void* d_ws, size_t ws_size,
                              hipStream_t stream) {
  const float* x    = (const float*)d_in[0];
  const float* fcos = (const float*)d_in[1];
  const float* fsin = (const float*)d_in[2];
  const float* Wq   = (const float*)d_in[3];
  const float* Wk   = (const float*)d_in[4];
  const float* Wv   = (const float*)d_in[5];
  const float* Wo   = (const float*)d_in[6];

  char* ws = (char*)d_ws;
  __bf16* xb  = (__bf16*)(ws);                       // 16 MB: x as bf16 (8192x1024)
  __bf16* Wqb = (__bf16*)(ws + (16u << 20));         // 2 MB each
  __bf16* Wkb = (__bf16*)(ws + (18u << 20));
  __bf16* Wvb = (__bf16*)(ws + (20u << 20));
  __bf16* Wob = (__bf16*)(ws + (22u << 20));
  __bf16* Qb  = (__bf16*)(ws + (24u << 20));         // 16 MB
  __bf16* Kb  = (__bf16*)(ws + (40u << 20));         // 16 MB
  __bf16* Vtb = (__bf16*)(ws + (56u << 20));         // 16 MB (ends at 72 MB)
  __bf16* Ub  = xb;  // x no longer needed after V projection

  cvt_bf16<<<8192, 256, 0, stream>>>(x,  xb,  8192 * 1024 / 4);
  cvt_bf16<<<1024, 256, 0, stream>>>(Wq, Wqb, 1024 * 1024 / 4);
  cvt_bf16<<<1024, 256, 0, stream>>>(Wk, Wkb, 1024 * 1024 / 4);
  cvt_bf16<<<1024, 256, 0, stream>>>(Wv, Wvb, 1024 * 1024 / 4);
  cvt_bf16<<<1024, 256, 0, stream>>>(Wo, Wob, 1024 * 1024 / 4);

  dim3 gg(8, 64);
  gemm_bt<0><<<gg, 256, 0, stream>>>(xb, Wqb, Qb,  fcos, fsin);
  gemm_bt<1><<<gg, 256, 0, stream>>>(xb, Wkb, Kb,  fcos, fsin);
  gemm_bt<2><<<gg, 256, 0, stream>>>(xb, Wvb, Vtb, nullptr, nullptr);
  attn_fwd<<<dim3(32, 64), 256, 0, stream>>>(Qb, Kb, Vtb, Ub);
  gemm_bt<3><<<gg, 256, 0, stream>>>(Ub, Wob, d_out, nullptr, nullptr);
}

// Round 2
// 348.137 us; speedup vs baseline: 1.0041x; 1.0041x over previous
//
#include <hip/hip_runtime.h>
#include <hip/hip_bf16.h>

typedef __attribute__((ext_vector_type(8))) __bf16 bf16x8;
typedef __attribute__((ext_vector_type(4))) __bf16 bf16x4;
typedef __attribute__((ext_vector_type(4))) float f32x4;

static __device__ __forceinline__ f32x4 mfma_bf16(bf16x8 a, bf16x8 b, f32x4 c) {
  return __builtin_amdgcn_mfma_f32_16x16x32_bf16(a, b, c, 0, 0, 0);
}

// async global->LDS, 16B per lane. LDS dest must be linear in lane order.
static __device__ __forceinline__ void gload_lds16(const void* g, void* l) {
  __builtin_amdgcn_global_load_lds(
      (__attribute__((address_space(1))) unsigned int*)g,
      (__attribute__((address_space(3))) unsigned int*)l, 16, 0, 0);
}

// ---------------------------------------------------------------- fp32 -> bf16
__global__ void cvt_bf16(const float* __restrict__ in, __bf16* __restrict__ out, int n4) {
  int i = blockIdx.x * blockDim.x + threadIdx.x;
  if (i >= n4) return;
  f32x4 v = ((const f32x4*)in)[i];
  bf16x4 o;
#pragma unroll
  for (int k = 0; k < 4; ++k) o[k] = (__bf16)v[k];
  ((bf16x4*)out)[i] = o;
}

// ---------------------------------------------------------------- GEMM  C = A @ W^T
// MODE 0: Q  -> rope + *0.125, bf16 token-major [m][n]
// MODE 1: K  -> rope,          bf16 token-major [m][n]
// MODE 2: V  -> bf16 TRANSPOSED [b*1024 + n][tok]   (i.e. [b,h,d,s])
// MODE 3: OUT-> fp32 [m][n] to d_out
template <int MODE>
__global__ __launch_bounds__(256, 2)
void gemm_bt(const __bf16* __restrict__ A, const __bf16* __restrict__ W,
             void* __restrict__ outp,
             const float* __restrict__ fcos, const float* __restrict__ fsin) {
  constexpr int K = 1024;
  constexpr int NCOL = 1024;
  __shared__ __align__(16) __bf16 Alds[128 * 32];
  __shared__ __align__(16) __bf16 Blds[128 * 32];
  const int t = threadIdx.x;
  const int lane = t & 63;
  const int wave = t >> 6;
  const int g = lane >> 4, ln = lane & 15;
  const int wm = wave >> 1, wn = wave & 1;  // 2x2 waves of 64x64
  const int bm = blockIdx.y, bn = blockIdx.x;

  f32x4 acc[4][4] = {};

  const int srow = t >> 2;         // 0..63
  const int scol = (t & 3) * 8;    // k-offset (elems)
  const __bf16* Ag = A + (size_t)(bm * 128 + srow) * K + scol;
  const __bf16* Wg = W + (size_t)(bn * 128 + srow) * K + scol;
  __bf16* la = Alds + t * 8;       // linear: row*32 + scol
  __bf16* lb = Blds + t * 8;

  for (int k0 = 0; k0 < K; k0 += 32) {
    gload_lds16(Ag + k0, la);
    gload_lds16(Ag + k0 + 64 * K, la + 2048);
    gload_lds16(Wg + k0, lb);
    gload_lds16(Wg + k0 + 64 * K, lb + 2048);
    __syncthreads();
    bf16x8 af[4], bfr[4];
#pragma unroll
    for (int i = 0; i < 4; ++i)
      af[i] = *(const bf16x8*)(Alds + (wm * 64 + i * 16 + ln) * 32 + g * 8);
#pragma unroll
    for (int j = 0; j < 4; ++j)
      bfr[j] = *(const bf16x8*)(Blds + (wn * 64 + j * 16 + ln) * 32 + g * 8);
#pragma unroll
    for (int i = 0; i < 4; ++i)
#pragma unroll
      for (int j = 0; j < 4; ++j)
        acc[i][j] = mfma_bf16(af[i], bfr[j], acc[i][j]);
    __syncthreads();
  }

  // Epilogue. D-layout: col = lane&15 (within 16), row = (lane>>4)*4 + r.
#pragma unroll
  for (int i = 0; i < 4; ++i) {
    const int mbase = bm * 128 + wm * 64 + i * 16 + g * 4;
#pragma unroll
    for (int j = 0; j < 4; ++j) {
      const int col = bn * 128 + wn * 64 + j * 16 + ln;
      if constexpr (MODE == 0 || MODE == 1) {
        const int fi = (col & 63) >> 1;
        const bool odd = (col & 1) != 0;
        __bf16* O = (__bf16*)outp;
#pragma unroll
        for (int r = 0; r < 4; ++r) {
          const int row = mbase + r;
          const int tok = row & 2047;
          const float cs = fcos[tok * 32 + fi];
          const float sn = fsin[tok * 32 + fi];
          const float own = acc[i][j][r];
          const float oth = __shfl_xor(own, 1);  // partner column d^1
          float val = own * cs + (odd ? oth * sn : -oth * sn);
          if constexpr (MODE == 0) val *= 0.125f;  // 1/sqrt(64)
          O[(size_t)row * NCOL + col] = (__bf16)val;
        }
      } else if constexpr (MODE == 2) {
        __bf16* O = (__bf16*)outp;
        const int bb = mbase >> 11;
        const int tok = mbase & 2047;
        bf16x4 pk;
#pragma unroll
        for (int r = 0; r < 4; ++r) pk[r] = (__bf16)acc[i][j][r];
        *(bf16x4*)(O + ((size_t)(bb * 1024 + col)) * 2048 + tok) = pk;
      } else {
        float* O = (float*)outp;
#pragma unroll
        for (int r = 0; r < 4; ++r)
          O[(size_t)(mbase + r) * NCOL + col] = acc[i][j][r];
      }
    }
  }
}

// ---------------------------------------------------------------- flash attention
// Q,K: bf16 token-major [b,s,h*64+d] (Q pre-scaled by 0.125, both rope'd).
// Vt:  bf16 [b*1024 + h*64 + d][s].
// U:   bf16 token-major [b,s,h*64+d].
// Block: 128 q-rows (4 waves x 32 = 2 frags of 16), KV tiles of 64, causal.
// 2-phase double-buffered staging: one barrier per KV tile, loads in flight
// across the compute of the current tile.
__global__ __launch_bounds__(256, 3)
void attn_fwd(const __bf16* __restrict__ Q, const __bf16* __restrict__ Kk,
              const __bf16* __restrict__ Vt, __bf16* __restrict__ U) {
  constexpr int S = 2048;
  __shared__ __align__(16) __bf16 Klds[2][2 * 64 * 32];  // [buf][dk-half][kv][32]
  __shared__ __align__(16) __bf16 Vlds[2][2 * 64 * 32];  // [buf][kv-half][d][32]
  __shared__ __align__(16) __bf16 Plds[8 * 1280];        // [wave*2+f][s*640+row*40+..]

  const int t = threadIdx.x;
  const int lane = t & 63, wave = t >> 6;
  const int g = lane >> 4, ln = lane & 15;
  const int qt = 15 - blockIdx.x;        // reversed: longest blocks dispatch first
  const int bh = blockIdx.y;
  const int b = bh >> 4, h = bh & 15;
  const int q0 = qt * 128;

  // Q fragments in registers: frag f covers rows q0+wave*32+f*16 .. +15
  bf16x8 qf[2][2];
#pragma unroll
  for (int f = 0; f < 2; ++f) {
    const __bf16* Qb = Q + ((size_t)(b * S + q0 + wave * 32 + f * 16 + ln)) * 1024 + h * 64;
    qf[f][0] = *(const bf16x8*)(Qb + g * 8);
    qf[f][1] = *(const bf16x8*)(Qb + 32 + g * 8);
  }

  f32x4 o[2][4] = {};
  float mrow[2][4], lrow[2][4];
#pragma unroll
  for (int f = 0; f < 2; ++f)
#pragma unroll
    for (int r = 0; r < 4; ++r) { mrow[f][r] = -3.0e38f; lrow[f][r] = 0.f; }

  const int srow = t >> 2;        // 0..63
  const int scol = (t & 3) * 8;
  const __bf16* Kg = Kk + ((size_t)(b * S + srow)) * 1024 + h * 64 + scol;
  const __bf16* Vg = Vt + ((size_t)(b * 1024 + h * 64 + srow)) * 2048 + scol;
  const int nt = 2 * qt + 2;

  // prologue: stage tile 0 into buf 0
  gload_lds16(Kg, Klds[0] + t * 8);
  gload_lds16(Kg + 32, Klds[0] + 2048 + t * 8);
  gload_lds16(Vg, Vlds[0] + t * 8);
  gload_lds16(Vg + 32, Vlds[0] + 2048 + t * 8);
  __syncthreads();

  for (int kt = 0; kt < nt; ++kt) {
    const int cur = kt & 1;
    if (kt + 1 < nt) {  // prefetch next tile into other buffer (overlaps compute)
      const size_t kv1 = (size_t)(kt + 1) * 64;
      gload_lds16(Kg + kv1 * 1024, Klds[cur ^ 1] + t * 8);
      gload_lds16(Kg + kv1 * 1024 + 32, Klds[cur ^ 1] + 2048 + t * 8);
      gload_lds16(Vg + kv1, Vlds[cur ^ 1] + t * 8);
      gload_lds16(Vg + kv1 + 32, Vlds[cur ^ 1] + 2048 + t * 8);
    }
    const int kv0 = kt * 64;

#pragma unroll
    for (int f = 0; f < 2; ++f) {
      // S = Q K^T : 16(q) x 64(kv) for this frag
      f32x4 sa[4] = {};
#pragma unroll
      for (int s = 0; s < 2; ++s) {
#pragma unroll
        for (int c = 0; c < 4; ++c) {
          bf16x8 kf = *(const bf16x8*)(Klds[cur] + s * 2048 + (c * 16 + ln) * 32 + g * 8);
          sa[c] = mfma_bf16(qf[f][s], kf, sa[c]);
        }
      }

      const int rfbase = q0 + wave * 32 + f * 16;
      if (kv0 + 63 > rfbase) {  // causal mask (only near the diagonal)
#pragma unroll
        for (int c = 0; c < 4; ++c) {
          const int colk = kv0 + c * 16 + ln;
#pragma unroll
          for (int r = 0; r < 4; ++r)
            if (colk > rfbase + g * 4 + r) sa[c][r] = -1e30f;
        }
      }

      // online softmax (rows live on 16-lane groups)
      float pm[4];
#pragma unroll
      for (int r = 0; r < 4; ++r)
        pm[r] = fmaxf(fmaxf(sa[0][r], sa[1][r]), fmaxf(sa[2][r], sa[3][r]));
#pragma unroll
      for (int off = 8; off >= 1; off >>= 1)
#pragma unroll
        for (int r = 0; r < 4; ++r) pm[r] = fmaxf(pm[r], __shfl_xor(pm[r], off));

      float alpha[4], rs[4];
#pragma unroll
      for (int r = 0; r < 4; ++r) {
        const float mn = fmaxf(mrow[f][r], pm[r]);
        alpha[r] = __expf(mrow[f][r] - mn);
        mrow[f][r] = mn;
        rs[r] = 0.f;
      }
      __bf16* Pw = Plds + (wave * 2 + f) * 1280;
#pragma unroll
      for (int c = 0; c < 4; ++c)
#pragma unroll
        for (int r = 0; r < 4; ++r) {
          const float p = __expf(sa[c][r] - mrow[f][r]);
          rs[r] += p;
          Pw[(c >> 1) * 640 + (g * 4 + r) * 40 + (c & 1) * 16 + ln] = (__bf16)p;
        }
#pragma unroll
      for (int off = 8; off >= 1; off >>= 1)
#pragma unroll
        for (int r = 0; r < 4; ++r) rs[r] += __shfl_xor(rs[r], off);
#pragma unroll
      for (int r = 0; r < 4; ++r) lrow[f][r] = lrow[f][r] * alpha[r] + rs[r];
#pragma unroll
      for (int c = 0; c < 4; ++c)
#pragma unroll
        for (int r = 0; r < 4; ++r) o[f][c][r] *= alpha[r];

      // O += P V (wave-local P through LDS; same-wave ordering, no barrier)
#pragma unroll
      for (int s = 0; s < 2; ++s) {
        bf16x8 pa = *(const bf16x8*)(Pw + s * 640 + ln * 40 + g * 8);
#pragma unroll
        for (int c = 0; c < 4; ++c) {
          bf16x8 vb = *(const bf16x8*)(Vlds[cur] + s * 2048 + (c * 16 + ln) * 32 + g * 8);
          o[f][c] = mfma_bf16(pa, vb, o[f][c]);
        }
      }
    }
    __syncthreads();  // drains prefetch vmcnt + protects buffer swap
  }

  // normalize + write U (token-major)
#pragma unroll
  for (int f = 0; f < 2; ++f) {
    __bf16* Ub = U + ((size_t)(b * S + q0 + wave * 32 + f * 16 + g * 4)) * 1024 + h * 64;
#pragma unroll
    for (int c = 0; c < 4; ++c)
#pragma unroll
      for (int r = 0; r < 4; ++r)
        Ub[(size_t)r * 1024 + c * 16 + ln] = (__bf16)(o[f][c][r] / lrow[f][r]);
  }
}

// ---------------------------------------------------------------- launch
extern "C" void kernel_launch(void* const* d_in, const int* in_sizes, int n_in,
                              void* d_out, int out_size, void* d_ws, size_t ws_size,
                              hipStream_t stream) {
  const float* x    = (const float*)d_in[0];
  const float* fcos = (const float*)d_in[1];
  const float* fsin = (const float*)d_in[2];
  const float* Wq   = (const float*)d_in[3];
  const float* Wk   = (const float*)d_in[4];
  const float* Wv   = (const float*)d_in[5];
  const float* Wo   = (const float*)d_in[6];

  char* ws = (char*)d_ws;
  __bf16* xb  = (__bf16*)(ws);                       // 16 MB: x as bf16 (8192x1024)
  __bf16* Wqb = (__bf16*)(ws + (16u << 20));         // 2 MB each
  __bf16* Wkb = (__bf16*)(ws + (18u << 20));
  __bf16* Wvb = (__bf16*)(ws + (20u << 20));
  __bf16* Wob = (__bf16*)(ws + (22u << 20));
  __bf16* Qb  = (__bf16*)(ws + (24u << 20));         // 16 MB
  __bf16* Kb  = (__bf16*)(ws + (40u << 20));         // 16 MB
  __bf16* Vtb = (__bf16*)(ws + (56u << 20));         // 16 MB (ends at 72 MB)
  __bf16* Ub  = xb;  // x no longer needed after V projection

  cvt_bf16<<<8192, 256, 0, stream>>>(x,  xb,  8192 * 1024 / 4);
  cvt_bf16<<<1024, 256, 0, stream>>>(Wq, Wqb, 1024 * 1024 / 4);
  cvt_bf16<<<1024, 256, 0, stream>>>(Wk, Wkb, 1024 * 1024 / 4);
  cvt_bf16<<<1024, 256, 0, stream>>>(Wv, Wvb, 1024 * 1024 / 4);
  cvt_bf16<<<1024, 256, 0, stream>>>(Wo, Wob, 1024 * 1024 / 4);

  dim3 gg(8, 64);
  gemm_bt<0><<<gg, 256, 0, stream>>>(xb, Wqb, Qb,  fcos, fsin);
  gemm_bt<1><<<gg, 256, 0, stream>>>(xb, Wkb, Kb,  fcos, fsin);
  gemm_bt<2><<<gg, 256, 0, stream>>>(xb, Wvb, Vtb, nullptr, nullptr);
  attn_fwd<<<dim3(16, 64), 256, 0, stream>>>(Qb, Kb, Vtb, Ub);
  gemm_bt<3><<<gg, 256, 0, stream>>>(Ub, Wob, d_out, nullptr, nullptr);
}

// Round 3
// 262.313 us; speedup vs baseline: 1.3326x; 1.3272x over previous
//
#include <hip/hip_runtime.h>
#include <hip/hip_bf16.h>

typedef __attribute__((ext_vector_type(8))) __bf16 bf16x8;
typedef __attribute__((ext_vector_type(4))) __bf16 bf16x4;
typedef __attribute__((ext_vector_type(4))) float f32x4;

static __device__ __forceinline__ f32x4 mfma_bf16(bf16x8 a, bf16x8 b, f32x4 c) {
  return __builtin_amdgcn_mfma_f32_16x16x32_bf16(a, b, c, 0, 0, 0);
}

// async global->LDS, 16B per lane. LDS dest must be linear in lane order.
static __device__ __forceinline__ void gload_lds16(const void* g, void* l) {
  __builtin_amdgcn_global_load_lds(
      (__attribute__((address_space(1))) unsigned int*)g,
      (__attribute__((address_space(3))) unsigned int*)l, 16, 0, 0);
}

// ---------------------------------------------------------------- fp32 -> bf16
__global__ void cvt_bf16(const float* __restrict__ in, __bf16* __restrict__ out, int n4) {
  int i = blockIdx.x * blockDim.x + threadIdx.x;
  if (i >= n4) return;
  f32x4 v = ((const f32x4*)in)[i];
  bf16x4 o;
#pragma unroll
  for (int k = 0; k < 4; ++k) o[k] = (__bf16)v[k];
  ((bf16x4*)out)[i] = o;
}

// ---------------------------------------------------------------- GEMM  C = A @ W^T
// MODE 0: Q  -> rope + *0.125, bf16 token-major [m][n]
// MODE 1: K  -> rope,          bf16 token-major [m][n]
// MODE 2: V  -> bf16 TRANSPOSED [b*1024 + n][tok]   (i.e. [b,h,d,s])
// MODE 3: OUT-> fp32 [m][n] to d_out
template <int MODE>
__global__ __launch_bounds__(256, 2)
void gemm_bt(const __bf16* __restrict__ A, const __bf16* __restrict__ W,
             void* __restrict__ outp,
             const float* __restrict__ fcos, const float* __restrict__ fsin) {
  constexpr int K = 1024;
  constexpr int NCOL = 1024;
  __shared__ __align__(16) __bf16 Alds[128 * 32];
  __shared__ __align__(16) __bf16 Blds[128 * 32];
  const int t = threadIdx.x;
  const int lane = t & 63;
  const int wave = t >> 6;
  const int g = lane >> 4, ln = lane & 15;
  const int wm = wave >> 1, wn = wave & 1;  // 2x2 waves of 64x64
  const int bm = blockIdx.y, bn = blockIdx.x;

  f32x4 acc[4][4] = {};

  const int srow = t >> 2;         // 0..63
  const int scol = (t & 3) * 8;    // k-offset (elems)
  const __bf16* Ag = A + (size_t)(bm * 128 + srow) * K + scol;
  const __bf16* Wg = W + (size_t)(bn * 128 + srow) * K + scol;
  __bf16* la = Alds + t * 8;       // linear: row*32 + scol
  __bf16* lb = Blds + t * 8;

  for (int k0 = 0; k0 < K; k0 += 32) {
    gload_lds16(Ag + k0, la);
    gload_lds16(Ag + k0 + 64 * K, la + 2048);
    gload_lds16(Wg + k0, lb);
    gload_lds16(Wg + k0 + 64 * K, lb + 2048);
    __syncthreads();
    bf16x8 af[4], bfr[4];
#pragma unroll
    for (int i = 0; i < 4; ++i)
      af[i] = *(const bf16x8*)(Alds + (wm * 64 + i * 16 + ln) * 32 + g * 8);
#pragma unroll
    for (int j = 0; j < 4; ++j)
      bfr[j] = *(const bf16x8*)(Blds + (wn * 64 + j * 16 + ln) * 32 + g * 8);
#pragma unroll
    for (int i = 0; i < 4; ++i)
#pragma unroll
      for (int j = 0; j < 4; ++j)
        acc[i][j] = mfma_bf16(af[i], bfr[j], acc[i][j]);
    __syncthreads();
  }

  // Epilogue. D-layout: col = lane&15 (within 16), row = (lane>>4)*4 + r.
#pragma unroll
  for (int i = 0; i < 4; ++i) {
    const int mbase = bm * 128 + wm * 64 + i * 16 + g * 4;
#pragma unroll
    for (int j = 0; j < 4; ++j) {
      const int col = bn * 128 + wn * 64 + j * 16 + ln;
      if constexpr (MODE == 0 || MODE == 1) {
        const int fi = (col & 63) >> 1;
        const bool odd = (col & 1) != 0;
        __bf16* O = (__bf16*)outp;
#pragma unroll
        for (int r = 0; r < 4; ++r) {
          const int row = mbase + r;
          const int tok = row & 2047;
          const float cs = fcos[tok * 32 + fi];
          const float sn = fsin[tok * 32 + fi];
          const float own = acc[i][j][r];
          const float oth = __shfl_xor(own, 1);  // partner column d^1
          float val = own * cs + (odd ? oth * sn : -oth * sn);
          if constexpr (MODE == 0) val *= 0.125f;  // 1/sqrt(64)
          O[(size_t)row * NCOL + col] = (__bf16)val;
        }
      } else if constexpr (MODE == 2) {
        __bf16* O = (__bf16*)outp;
        const int bb = mbase >> 11;
        const int tok = mbase & 2047;
        bf16x4 pk;
#pragma unroll
        for (int r = 0; r < 4; ++r) pk[r] = (__bf16)acc[i][j][r];
        *(bf16x4*)(O + ((size_t)(bb * 1024 + col)) * 2048 + tok) = pk;
      } else {
        float* O = (float*)outp;
#pragma unroll
        for (int r = 0; r < 4; ++r)
          O[(size_t)(mbase + r) * NCOL + col] = acc[i][j][r];
      }
    }
  }
}

// ---------------------------------------------------------------- flash attention
// Q,K: bf16 token-major [b,s,h*64+d] (Q pre-scaled by 0.125, both rope'd).
// Vt:  bf16 [b*1024 + h*64 + d][s].
// U:   bf16 token-major [b,s,h*64+d].
//
// Load-balanced paired strips: block (qt, bh) handles q-strips qt*128 and
// (15-qt)*128 (qt=0..7). Work = (2qt+2)+(32-2qt) = 34 KV tiles -- uniform.
// Grid = 512 blocks -> ALL co-resident (2/CU), no tail. Shared-prefix KV
// staging: while both strips are active they consume the same staged tile
// (64 MFMA/wave/tile). Double-buffered prefetch, one barrier per tile.
__global__ __launch_bounds__(256, 2)
void attn_fwd(const __bf16* __restrict__ Q, const __bf16* __restrict__ Kk,
              const __bf16* __restrict__ Vt, __bf16* __restrict__ U) {
  constexpr int S = 2048;
  __shared__ __align__(16) __bf16 Klds[2][2 * 64 * 32];  // [buf][dk-half][kv][32]
  __shared__ __align__(16) __bf16 Vlds[2][2 * 64 * 32];  // [buf][kv-half][d][32]
  __shared__ __align__(16) __bf16 Plds[8 * 1280];        // [wave*2+f][s*640+row*40+..]

  const int t = threadIdx.x;
  const int lane = t & 63, wave = t >> 6;
  const int g = lane >> 4, ln = lane & 15;
  const int qt = blockIdx.x;             // 0..7
  const int bh = blockIdx.y;
  const int b = bh >> 4, h = bh & 15;
  const int q0s[2] = {qt * 128, (15 - qt) * 128};
  const int nts[2] = {2 * qt + 2, 32 - 2 * qt};   // nts[1] > nts[0] always

  // Q fragments in registers: strip s2, frag f covers rows q0+wave*32+f*16..+15
  bf16x8 qf[2][2][2];
#pragma unroll
  for (int s2 = 0; s2 < 2; ++s2)
#pragma unroll
    for (int f = 0; f < 2; ++f) {
      const __bf16* Qb =
          Q + ((size_t)(b * S + q0s[s2] + wave * 32 + f * 16 + ln)) * 1024 + h * 64;
      qf[s2][f][0] = *(const bf16x8*)(Qb + g * 8);
      qf[s2][f][1] = *(const bf16x8*)(Qb + 32 + g * 8);
    }

  f32x4 o[2][2][4] = {};
  float mrow[2][2][4], lrow[2][2][4];
#pragma unroll
  for (int s2 = 0; s2 < 2; ++s2)
#pragma unroll
    for (int f = 0; f < 2; ++f)
#pragma unroll
      for (int r = 0; r < 4; ++r) { mrow[s2][f][r] = -3.0e38f; lrow[s2][f][r] = 0.f; }

  const int srow = t >> 2;        // 0..63
  const int scol = (t & 3) * 8;
  const __bf16* Kg = Kk + ((size_t)(b * S + srow)) * 1024 + h * 64 + scol;
  const __bf16* Vg = Vt + ((size_t)(b * 1024 + h * 64 + srow)) * 2048 + scol;
  const int nt = nts[1];

  // prologue: stage tile 0 into buf 0
  gload_lds16(Kg, Klds[0] + t * 8);
  gload_lds16(Kg + 32, Klds[0] + 2048 + t * 8);
  gload_lds16(Vg, Vlds[0] + t * 8);
  gload_lds16(Vg + 32, Vlds[0] + 2048 + t * 8);
  __syncthreads();

  for (int kt = 0; kt < nt; ++kt) {
    const int cur = kt & 1;
    if (kt + 1 < nt) {  // prefetch next tile into other buffer (overlaps compute)
      const size_t kv1 = (size_t)(kt + 1) * 64;
      gload_lds16(Kg + kv1 * 1024, Klds[cur ^ 1] + t * 8);
      gload_lds16(Kg + kv1 * 1024 + 32, Klds[cur ^ 1] + 2048 + t * 8);
      gload_lds16(Vg + kv1, Vlds[cur ^ 1] + t * 8);
      gload_lds16(Vg + kv1 + 32, Vlds[cur ^ 1] + 2048 + t * 8);
    }
    const int kv0 = kt * 64;

#pragma unroll
    for (int s2 = 0; s2 < 2; ++s2) {
      if (kt >= nts[s2]) continue;  // block-uniform branch
#pragma unroll
      for (int f = 0; f < 2; ++f) {
        // S = Q K^T : 16(q) x 64(kv) for this frag
        f32x4 sa[4] = {};
        __builtin_amdgcn_s_setprio(1);
#pragma unroll
        for (int s = 0; s < 2; ++s) {
#pragma unroll
          for (int c = 0; c < 4; ++c) {
            bf16x8 kf = *(const bf16x8*)(Klds[cur] + s * 2048 + (c * 16 + ln) * 32 + g * 8);
            sa[c] = mfma_bf16(qf[s2][f][s], kf, sa[c]);
          }
        }
        __builtin_amdgcn_s_setprio(0);

        const int rfbase = q0s[s2] + wave * 32 + f * 16;
        if (kv0 + 63 > rfbase) {  // causal mask (only near the diagonal)
#pragma unroll
          for (int c = 0; c < 4; ++c) {
            const int colk = kv0 + c * 16 + ln;
#pragma unroll
            for (int r = 0; r < 4; ++r)
              if (colk > rfbase + g * 4 + r) sa[c][r] = -1e30f;
          }
        }

        // online softmax (rows live on 16-lane groups)
        float pm[4];
#pragma unroll
        for (int r = 0; r < 4; ++r)
          pm[r] = fmaxf(fmaxf(sa[0][r], sa[1][r]), fmaxf(sa[2][r], sa[3][r]));
#pragma unroll
        for (int off = 8; off >= 1; off >>= 1)
#pragma unroll
          for (int r = 0; r < 4; ++r) pm[r] = fmaxf(pm[r], __shfl_xor(pm[r], off));

        float alpha[4], rs[4];
#pragma unroll
        for (int r = 0; r < 4; ++r) {
          const float mn = fmaxf(mrow[s2][f][r], pm[r]);
          alpha[r] = __expf(mrow[s2][f][r] - mn);
          mrow[s2][f][r] = mn;
          rs[r] = 0.f;
        }
        __bf16* Pw = Plds + (wave * 2 + f) * 1280;
#pragma unroll
        for (int c = 0; c < 4; ++c)
#pragma unroll
          for (int r = 0; r < 4; ++r) {
            const float p = __expf(sa[c][r] - mrow[s2][f][r]);
            rs[r] += p;
            Pw[(c >> 1) * 640 + (g * 4 + r) * 40 + (c & 1) * 16 + ln] = (__bf16)p;
          }
#pragma unroll
        for (int off = 8; off >= 1; off >>= 1)
#pragma unroll
          for (int r = 0; r < 4; ++r) rs[r] += __shfl_xor(rs[r], off);
#pragma unroll
        for (int r = 0; r < 4; ++r) lrow[s2][f][r] = lrow[s2][f][r] * alpha[r] + rs[r];
#pragma unroll
        for (int c = 0; c < 4; ++c)
#pragma unroll
          for (int r = 0; r < 4; ++r) o[s2][f][c][r] *= alpha[r];

        // O += P V (wave-local P through LDS; same-wave ordering, no barrier)
        __builtin_amdgcn_s_setprio(1);
#pragma unroll
        for (int s = 0; s < 2; ++s) {
          bf16x8 pa = *(const bf16x8*)(Pw + s * 640 + ln * 40 + g * 8);
#pragma unroll
          for (int c = 0; c < 4; ++c) {
            bf16x8 vb = *(const bf16x8*)(Vlds[cur] + s * 2048 + (c * 16 + ln) * 32 + g * 8);
            o[s2][f][c] = mfma_bf16(pa, vb, o[s2][f][c]);
          }
        }
        __builtin_amdgcn_s_setprio(0);
      }
    }
    __syncthreads();  // drains prefetch vmcnt + protects buffer swap
  }

  // normalize + write U (token-major)
#pragma unroll
  for (int s2 = 0; s2 < 2; ++s2)
#pragma unroll
    for (int f = 0; f < 2; ++f) {
      __bf16* Ub =
          U + ((size_t)(b * S + q0s[s2] + wave * 32 + f * 16 + g * 4)) * 1024 + h * 64;
#pragma unroll
      for (int c = 0; c < 4; ++c)
#pragma unroll
        for (int r = 0; r < 4; ++r)
          Ub[(size_t)r * 1024 + c * 16 + ln] = (__bf16)(o[s2][f][c][r] / lrow[s2][f][r]);
    }
}

// ---------------------------------------------------------------- launch
extern "C" void kernel_launch(void* const* d_in, const int* in_sizes, int n_in,
                              void* d_out, int out_size, void* d_ws, size_t ws_size,
                              hipStream_t stream) {
  const float* x    = (const float*)d_in[0];
  const float* fcos = (const float*)d_in[1];
  const float* fsin = (const float*)d_in[2];
  const float* Wq   = (const float*)d_in[3];
  const float* Wk   = (const float*)d_in[4];
  const float* Wv   = (const float*)d_in[5];
  const float* Wo   = (const float*)d_in[6];

  char* ws = (char*)d_ws;
  __bf16* xb  = (__bf16*)(ws);                       // 16 MB: x as bf16 (8192x1024)
  __bf16* Wqb = (__bf16*)(ws + (16u << 20));         // 2 MB each
  __bf16* Wkb = (__bf16*)(ws + (18u << 20));
  __bf16* Wvb = (__bf16*)(ws + (20u << 20));
  __bf16* Wob = (__bf16*)(ws + (22u << 20));
  __bf16* Qb  = (__bf16*)(ws + (24u << 20));         // 16 MB
  __bf16* Kb  = (__bf16*)(ws + (40u << 20));         // 16 MB
  __bf16* Vtb = (__bf16*)(ws + (56u << 20));         // 16 MB (ends at 72 MB)
  __bf16* Ub  = xb;  // x no longer needed after V projection

  cvt_bf16<<<8192, 256, 0, stream>>>(x,  xb,  8192 * 1024 / 4);
  cvt_bf16<<<1024, 256, 0, stream>>>(Wq, Wqb, 1024 * 1024 / 4);
  cvt_bf16<<<1024, 256, 0, stream>>>(Wk, Wkb, 1024 * 1024 / 4);
  cvt_bf16<<<1024, 256, 0, stream>>>(Wv, Wvb, 1024 * 1024 / 4);
  cvt_bf16<<<1024, 256, 0, stream>>>(Wo, Wob, 1024 * 1024 / 4);

  dim3 gg(8, 64);
  gemm_bt<0><<<gg, 256, 0, stream>>>(xb, Wqb, Qb,  fcos, fsin);
  gemm_bt<1><<<gg, 256, 0, stream>>>(xb, Wkb, Kb,  fcos, fsin);
  gemm_bt<2><<<gg, 256, 0, stream>>>(xb, Wvb, Vtb, nullptr, nullptr);
  attn_fwd<<<dim3(8, 64), 256, 0, stream>>>(Qb, Kb, Vtb, Ub);
  gemm_bt<3><<<gg, 256, 0, stream>>>(Ub, Wob, d_out, nullptr, nullptr);
}

// Round 4
// 254.058 us; speedup vs baseline: 1.3759x; 1.0325x over previous
//
#include <hip/hip_runtime.h>
#include <hip/hip_bf16.h>

typedef __attribute__((ext_vector_type(8))) __bf16 bf16x8;
typedef __attribute__((ext_vector_type(4))) __bf16 bf16x4;
typedef __attribute__((ext_vector_type(4))) float f32x4;

static __device__ __forceinline__ f32x4 mfma_bf16(bf16x8 a, bf16x8 b, f32x4 c) {
  return __builtin_amdgcn_mfma_f32_16x16x32_bf16(a, b, c, 0, 0, 0);
}

// async global->LDS, 16B per lane. LDS dest must be linear in lane order.
static __device__ __forceinline__ void gload_lds16(const void* g, void* l) {
  __builtin_amdgcn_global_load_lds(
      (__attribute__((address_space(1))) unsigned int*)g,
      (__attribute__((address_space(3))) unsigned int*)l, 16, 0, 0);
}

// ---------------------------------------------------------------- fp32 -> bf16
__global__ void cvt_bf16(const float* __restrict__ in, __bf16* __restrict__ out, int n4) {
  int i = blockIdx.x * blockDim.x + threadIdx.x;
  if (i >= n4) return;
  f32x4 v = ((const f32x4*)in)[i];
  bf16x4 o;
#pragma unroll
  for (int k = 0; k < 4; ++k) o[k] = (__bf16)v[k];
  ((bf16x4*)out)[i] = o;
}

// ---------------------------------------------------------------- GEMM  C = A @ W^T
// MODE 0: Q  -> rope + *0.125*log2(e)  (attn softmax runs in exp2 units)
// MODE 1: K  -> rope,          bf16 token-major [m][n]
// MODE 2: V  -> bf16 TRANSPOSED [b*1024 + n][tok]   (i.e. [b,h,d,s])
// MODE 3: OUT-> fp32 [m][n] to d_out
template <int MODE>
__global__ __launch_bounds__(256, 2)
void gemm_bt(const __bf16* __restrict__ A, const __bf16* __restrict__ W,
             void* __restrict__ outp,
             const float* __restrict__ fcos, const float* __restrict__ fsin) {
  constexpr int K = 1024;
  constexpr int NCOL = 1024;
  __shared__ __align__(16) __bf16 Alds[128 * 32];
  __shared__ __align__(16) __bf16 Blds[128 * 32];
  const int t = threadIdx.x;
  const int lane = t & 63;
  const int wave = t >> 6;
  const int g = lane >> 4, ln = lane & 15;
  const int wm = wave >> 1, wn = wave & 1;  // 2x2 waves of 64x64
  const int bm = blockIdx.y, bn = blockIdx.x;

  f32x4 acc[4][4] = {};

  const int srow = t >> 2;         // 0..63
  const int scol = (t & 3) * 8;    // k-offset (elems)
  const __bf16* Ag = A + (size_t)(bm * 128 + srow) * K + scol;
  const __bf16* Wg = W + (size_t)(bn * 128 + srow) * K + scol;
  __bf16* la = Alds + t * 8;       // linear: row*32 + scol
  __bf16* lb = Blds + t * 8;

  for (int k0 = 0; k0 < K; k0 += 32) {
    gload_lds16(Ag + k0, la);
    gload_lds16(Ag + k0 + 64 * K, la + 2048);
    gload_lds16(Wg + k0, lb);
    gload_lds16(Wg + k0 + 64 * K, lb + 2048);
    __syncthreads();
    bf16x8 af[4], bfr[4];
#pragma unroll
    for (int i = 0; i < 4; ++i)
      af[i] = *(const bf16x8*)(Alds + (wm * 64 + i * 16 + ln) * 32 + g * 8);
#pragma unroll
    for (int j = 0; j < 4; ++j)
      bfr[j] = *(const bf16x8*)(Blds + (wn * 64 + j * 16 + ln) * 32 + g * 8);
#pragma unroll
    for (int i = 0; i < 4; ++i)
#pragma unroll
      for (int j = 0; j < 4; ++j)
        acc[i][j] = mfma_bf16(af[i], bfr[j], acc[i][j]);
    __syncthreads();
  }

  // Epilogue. D-layout: col = lane&15 (within 16), row = (lane>>4)*4 + r.
#pragma unroll
  for (int i = 0; i < 4; ++i) {
    const int mbase = bm * 128 + wm * 64 + i * 16 + g * 4;
#pragma unroll
    for (int j = 0; j < 4; ++j) {
      const int col = bn * 128 + wn * 64 + j * 16 + ln;
      if constexpr (MODE == 0 || MODE == 1) {
        const int fi = (col & 63) >> 1;
        const bool odd = (col & 1) != 0;
        __bf16* O = (__bf16*)outp;
#pragma unroll
        for (int r = 0; r < 4; ++r) {
          const int row = mbase + r;
          const int tok = row & 2047;
          const float cs = fcos[tok * 32 + fi];
          const float sn = fsin[tok * 32 + fi];
          const float own = acc[i][j][r];
          const float oth = __shfl_xor(own, 1);  // partner column d^1
          float val = own * cs + (odd ? oth * sn : -oth * sn);
          if constexpr (MODE == 0) val *= 0.1803368802f;  // 0.125 * log2(e)
          O[(size_t)row * NCOL + col] = (__bf16)val;
        }
      } else if constexpr (MODE == 2) {
        __bf16* O = (__bf16*)outp;
        const int bb = mbase >> 11;
        const int tok = mbase & 2047;
        bf16x4 pk;
#pragma unroll
        for (int r = 0; r < 4; ++r) pk[r] = (__bf16)acc[i][j][r];
        *(bf16x4*)(O + ((size_t)(bb * 1024 + col)) * 2048 + tok) = pk;
      } else {
        float* O = (float*)outp;
#pragma unroll
        for (int r = 0; r < 4; ++r)
          O[(size_t)(mbase + r) * NCOL + col] = acc[i][j][r];
      }
    }
  }
}

// ---------------------------------------------------------------- flash attention
// Q,K: bf16 token-major [b,s,h*64+d]; Q pre-scaled by 0.125*log2(e) (exp2 units).
// Vt:  bf16 [b*1024 + h*64 + d][s].
// U:   bf16 token-major [b,s,h*64+d].
//
// 512-thread blocks (8 waves). Block (qt, bh) handles q-strips qt*128 and
// (15-qt)*128; each wave owns 16 q-rows of each strip. Work = 34 strip-tiles
// uniform. 512 blocks -> 2/CU -> 16 waves/CU. Double-buffered KV staging,
// one barrier per tile; defer-max online softmax (exp2 units).
__global__ __launch_bounds__(512, 4)
void attn_fwd(const __bf16* __restrict__ Q, const __bf16* __restrict__ Kk,
              const __bf16* __restrict__ Vt, __bf16* __restrict__ U) {
  constexpr int S = 2048;
  __shared__ __align__(16) __bf16 Klds[2][2 * 64 * 32];  // [buf][dk-half][kv][32]
  __shared__ __align__(16) __bf16 Vlds[2][2 * 64 * 32];  // [buf][kv-half][d][32]
  __shared__ __align__(16) __bf16 Plds[8][1280];         // per wave: [s][row][40]

  const int t = threadIdx.x;
  const int lane = t & 63, wave = t >> 6;
  const int g = lane >> 4, ln = lane & 15;
  const int qt = blockIdx.x;             // 0..7
  const int bh = blockIdx.y;
  const int b = bh >> 4, h = bh & 15;
  const int q0s[2] = {qt * 128, (15 - qt) * 128};
  const int nts[2] = {2 * qt + 2, 32 - 2 * qt};   // nts[1] > nts[0] always

  // Q fragments: strip s2, this wave's rows q0+wave*16+ln, k-halves 0/1
  bf16x8 qf[2][2];
#pragma unroll
  for (int s2 = 0; s2 < 2; ++s2) {
    const __bf16* Qb = Q + ((size_t)(b * S + q0s[s2] + wave * 16 + ln)) * 1024 + h * 64;
    qf[s2][0] = *(const bf16x8*)(Qb + g * 8);
    qf[s2][1] = *(const bf16x8*)(Qb + 32 + g * 8);
  }

  f32x4 o[2][4] = {};
  float mrow[2][4], lrow[2][4];
#pragma unroll
  for (int s2 = 0; s2 < 2; ++s2)
#pragma unroll
    for (int r = 0; r < 4; ++r) { mrow[s2][r] = -3.0e38f; lrow[s2][r] = 0.f; }

  // staging: 512 threads cover one 8KB tile (4096 elems) per call
  const int half = t >> 8;          // 0,1
  const int srow = (t >> 2) & 63;   // 0..63
  const int scol = (t & 3) * 8;
  const __bf16* Kg = Kk + ((size_t)(b * S + srow)) * 1024 + h * 64 + half * 32 + scol;
  const __bf16* Vg = Vt + ((size_t)(b * 1024 + h * 64 + srow)) * 2048 + half * 32 + scol;
  const int nt = nts[1];

  // prologue: stage tile 0 into buf 0
  gload_lds16(Kg, (__bf16*)Klds[0] + t * 8);
  gload_lds16(Vg, (__bf16*)Vlds[0] + t * 8);
  __syncthreads();

  for (int kt = 0; kt < nt; ++kt) {
    const int cur = kt & 1;
    if (kt + 1 < nt) {  // prefetch next tile into other buffer (overlaps compute)
      const size_t kv1 = (size_t)(kt + 1) * 64;
      gload_lds16(Kg + kv1 * 1024, (__bf16*)Klds[cur ^ 1] + t * 8);
      gload_lds16(Vg + kv1, (__bf16*)Vlds[cur ^ 1] + t * 8);
    }
    const int kv0 = kt * 64;

#pragma unroll
    for (int s2 = 0; s2 < 2; ++s2) {
      if (kt >= nts[s2]) continue;  // block-uniform branch
      // S = Q K^T : 16(q) x 64(kv); lane holds S[q=g*4+r][kv=c*16+ln]
      f32x4 sa[4] = {};
      __builtin_amdgcn_s_setprio(1);
#pragma unroll
      for (int s = 0; s < 2; ++s) {
#pragma unroll
        for (int c = 0; c < 4; ++c) {
          bf16x8 kf = *(const bf16x8*)(Klds[cur] + s * 2048 + (c * 16 + ln) * 32 + g * 8);
          sa[c] = mfma_bf16(qf[s2][s], kf, sa[c]);
        }
      }
      __builtin_amdgcn_s_setprio(0);

      const int rfbase = q0s[s2] + wave * 16;
      if (kv0 + 63 > rfbase) {  // causal mask (only near the diagonal)
#pragma unroll
        for (int c = 0; c < 4; ++c) {
          const int colk = kv0 + c * 16 + ln;
#pragma unroll
          for (int r = 0; r < 4; ++r)
            if (colk > rfbase + g * 4 + r) sa[c][r] = -1e30f;
        }
      }

      // online softmax with defer-max (all values in log2 units)
      float pm[4];
#pragma unroll
      for (int r = 0; r < 4; ++r)
        pm[r] = fmaxf(fmaxf(sa[0][r], sa[1][r]), fmaxf(sa[2][r], sa[3][r]));
      int need = 0;
#pragma unroll
      for (int r = 0; r < 4; ++r) need |= (pm[r] > mrow[s2][r] + 8.f) ? 1 : 0;
      if (__any(need)) {
#pragma unroll
        for (int off = 8; off >= 1; off >>= 1)
#pragma unroll
          for (int r = 0; r < 4; ++r) pm[r] = fmaxf(pm[r], __shfl_xor(pm[r], off));
#pragma unroll
        for (int r = 0; r < 4; ++r) {
          const float mn = fmaxf(mrow[s2][r], pm[r]);
          const float alpha = exp2f(mrow[s2][r] - mn);
          mrow[s2][r] = mn;
          lrow[s2][r] *= alpha;
#pragma unroll
          for (int c = 0; c < 4; ++c) o[s2][c][r] *= alpha;
        }
      }

      float rs[4] = {0.f, 0.f, 0.f, 0.f};
      __bf16* Pw = Plds[wave];
#pragma unroll
      for (int c = 0; c < 4; ++c)
#pragma unroll
        for (int r = 0; r < 4; ++r) {
          const float p = exp2f(sa[c][r] - mrow[s2][r]);
          rs[r] += p;
          Pw[(c >> 1) * 640 + (g * 4 + r) * 40 + (c & 1) * 16 + ln] = (__bf16)p;
        }
#pragma unroll
      for (int off = 8; off >= 1; off >>= 1)
#pragma unroll
        for (int r = 0; r < 4; ++r) rs[r] += __shfl_xor(rs[r], off);
#pragma unroll
      for (int r = 0; r < 4; ++r) lrow[s2][r] += rs[r];

      // O += P V (wave-local P through LDS; same-wave ordering, no barrier)
      __builtin_amdgcn_s_setprio(1);
#pragma unroll
      for (int s = 0; s < 2; ++s) {
        bf16x8 pa = *(const bf16x8*)(Pw + s * 640 + ln * 40 + g * 8);
#pragma unroll
        for (int c = 0; c < 4; ++c) {
          bf16x8 vb = *(const bf16x8*)(Vlds[cur] + s * 2048 + (c * 16 + ln) * 32 + g * 8);
          o[s2][c] = mfma_bf16(pa, vb, o[s2][c]);
        }
      }
      __builtin_amdgcn_s_setprio(0);
    }
    __syncthreads();  // drains prefetch vmcnt + protects buffer swap
  }

  // normalize + write U (token-major)
#pragma unroll
  for (int s2 = 0; s2 < 2; ++s2) {
    __bf16* Ub = U + ((size_t)(b * S + q0s[s2] + wave * 16 + g * 4)) * 1024 + h * 64;
#pragma unroll
    for (int c = 0; c < 4; ++c)
#pragma unroll
      for (int r = 0; r < 4; ++r)
        Ub[(size_t)r * 1024 + c * 16 + ln] = (__bf16)(o[s2][c][r] / lrow[s2][r]);
  }
}

// ---------------------------------------------------------------- launch
extern "C" void kernel_launch(void* const* d_in, const int* in_sizes, int n_in,
                              void* d_out, int out_size, void* d_ws, size_t ws_size,
                              hipStream_t stream) {
  const float* x    = (const float*)d_in[0];
  const float* fcos = (const float*)d_in[1];
  const float* fsin = (const float*)d_in[2];
  const float* Wq   = (const float*)d_in[3];
  const float* Wk   = (const float*)d_in[4];
  const float* Wv   = (const float*)d_in[5];
  const float* Wo   = (const float*)d_in[6];

  char* ws = (char*)d_ws;
  __bf16* xb  = (__bf16*)(ws);                       // 16 MB: x as bf16 (8192x1024)
  __bf16* Wqb = (__bf16*)(ws + (16u << 20));         // 2 MB each
  __bf16* Wkb = (__bf16*)(ws + (18u << 20));
  __bf16* Wvb = (__bf16*)(ws + (20u << 20));
  __bf16* Wob = (__bf16*)(ws + (22u << 20));
  __bf16* Qb  = (__bf16*)(ws + (24u << 20));         // 16 MB
  __bf16* Kb  = (__bf16*)(ws + (40u << 20));         // 16 MB
  __bf16* Vtb = (__bf16*)(ws + (56u << 20));         // 16 MB (ends at 72 MB)
  __bf16* Ub  = xb;  // x no longer needed after V projection

  cvt_bf16<<<8192, 256, 0, stream>>>(x,  xb,  8192 * 1024 / 4);
  cvt_bf16<<<1024, 256, 0, stream>>>(Wq, Wqb, 1024 * 1024 / 4);
  cvt_bf16<<<1024, 256, 0, stream>>>(Wk, Wkb, 1024 * 1024 / 4);
  cvt_bf16<<<1024, 256, 0, stream>>>(Wv, Wvb, 1024 * 1024 / 4);
  cvt_bf16<<<1024, 256, 0, stream>>>(Wo, Wob, 1024 * 1024 / 4);

  dim3 gg(8, 64);
  gemm_bt<0><<<gg, 256, 0, stream>>>(xb, Wqb, Qb,  fcos, fsin);
  gemm_bt<1><<<gg, 256, 0, stream>>>(xb, Wkb, Kb,  fcos, fsin);
  gemm_bt<2><<<gg, 256, 0, stream>>>(xb, Wvb, Vtb, nullptr, nullptr);
  attn_fwd<<<dim3(8, 64), 512, 0, stream>>>(Qb, Kb, Vtb, Ub);
  gemm_bt<3><<<gg, 256, 0, stream>>>(Ub, Wob, d_out, nullptr, nullptr);
}

// Round 5
// 226.127 us; speedup vs baseline: 1.5458x; 1.1235x over previous
//
#include <hip/hip_runtime.h>
#include <hip/hip_bf16.h>

typedef __attribute__((ext_vector_type(8))) __bf16 bf16x8;
typedef __attribute__((ext_vector_type(4))) __bf16 bf16x4;
typedef __attribute__((ext_vector_type(4))) float f32x4;
typedef __attribute__((ext_vector_type(2))) unsigned int u32x2;

static __device__ __forceinline__ f32x4 mfma_bf16(bf16x8 a, bf16x8 b, f32x4 c) {
  return __builtin_amdgcn_mfma_f32_16x16x32_bf16(a, b, c, 0, 0, 0);
}

// async global->LDS, 16B per lane. LDS dest must be linear in lane order.
static __device__ __forceinline__ void gload_lds16(const void* g, void* l) {
  __builtin_amdgcn_global_load_lds(
      (__attribute__((address_space(1))) unsigned int*)g,
      (__attribute__((address_space(3))) unsigned int*)l, 16, 0, 0);
}

static __device__ __forceinline__ unsigned int pk_bf16(float a, float b) {
  union { __bf16 h; unsigned short u; } x, y;
  x.h = (__bf16)a; y.h = (__bf16)b;
  return ((unsigned int)y.u << 16) | x.u;
}

// ---------------------------------------------------------------- fp32 -> bf16
__global__ void cvt_bf16(const float* __restrict__ in, __bf16* __restrict__ out, int n4) {
  int i = blockIdx.x * blockDim.x + threadIdx.x;
  if (i >= n4) return;
  f32x4 v = ((const f32x4*)in)[i];
  bf16x4 o;
#pragma unroll
  for (int k = 0; k < 4; ++k) o[k] = (__bf16)v[k];
  ((bf16x4*)out)[i] = o;
}

// ---------------------------------------------------------------- GEMM  C = A @ W^T
// MODE 0: Q  -> rope + *0.125*log2(e)  (attn softmax runs in exp2 units)
// MODE 1: K  -> rope,          bf16 token-major [m][n]
// MODE 2: V  -> bf16 TRANSPOSED [b*1024 + n][tok]   (i.e. [b,h,d,s])
// MODE 3: OUT-> fp32 [m][n] to d_out
template <int MODE>
__global__ __launch_bounds__(256, 2)
void gemm_bt(const __bf16* __restrict__ A, const __bf16* __restrict__ W,
             void* __restrict__ outp,
             const float* __restrict__ fcos, const float* __restrict__ fsin) {
  constexpr int K = 1024;
  constexpr int NCOL = 1024;
  __shared__ __align__(16) __bf16 Alds[128 * 32];
  __shared__ __align__(16) __bf16 Blds[128 * 32];
  const int t = threadIdx.x;
  const int lane = t & 63;
  const int wave = t >> 6;
  const int g = lane >> 4, ln = lane & 15;
  const int wm = wave >> 1, wn = wave & 1;  // 2x2 waves of 64x64
  const int bm = blockIdx.y, bn = blockIdx.x;

  f32x4 acc[4][4] = {};

  const int srow = t >> 2;         // 0..63
  const int scol = (t & 3) * 8;    // k-offset (elems)
  const __bf16* Ag = A + (size_t)(bm * 128 + srow) * K + scol;
  const __bf16* Wg = W + (size_t)(bn * 128 + srow) * K + scol;
  __bf16* la = Alds + t * 8;       // linear: row*32 + scol
  __bf16* lb = Blds + t * 8;

  for (int k0 = 0; k0 < K; k0 += 32) {
    gload_lds16(Ag + k0, la);
    gload_lds16(Ag + k0 + 64 * K, la + 2048);
    gload_lds16(Wg + k0, lb);
    gload_lds16(Wg + k0 + 64 * K, lb + 2048);
    __syncthreads();
    bf16x8 af[4], bfr[4];
#pragma unroll
    for (int i = 0; i < 4; ++i)
      af[i] = *(const bf16x8*)(Alds + (wm * 64 + i * 16 + ln) * 32 + g * 8);
#pragma unroll
    for (int j = 0; j < 4; ++j)
      bfr[j] = *(const bf16x8*)(Blds + (wn * 64 + j * 16 + ln) * 32 + g * 8);
#pragma unroll
    for (int i = 0; i < 4; ++i)
#pragma unroll
      for (int j = 0; j < 4; ++j)
        acc[i][j] = mfma_bf16(af[i], bfr[j], acc[i][j]);
    __syncthreads();
  }

  // Epilogue. D-layout: col = lane&15 (within 16), row = (lane>>4)*4 + r.
#pragma unroll
  for (int i = 0; i < 4; ++i) {
    const int mbase = bm * 128 + wm * 64 + i * 16 + g * 4;
#pragma unroll
    for (int j = 0; j < 4; ++j) {
      const int col = bn * 128 + wn * 64 + j * 16 + ln;
      if constexpr (MODE == 0 || MODE == 1) {
        const int fi = (col & 63) >> 1;
        const bool odd = (col & 1) != 0;
        __bf16* O = (__bf16*)outp;
#pragma unroll
        for (int r = 0; r < 4; ++r) {
          const int row = mbase + r;
          const int tok = row & 2047;
          const float cs = fcos[tok * 32 + fi];
          const float sn = fsin[tok * 32 + fi];
          const float own = acc[i][j][r];
          const float oth = __shfl_xor(own, 1);  // partner column d^1
          float val = own * cs + (odd ? oth * sn : -oth * sn);
          if constexpr (MODE == 0) val *= 0.1803368802f;  // 0.125 * log2(e)
          O[(size_t)row * NCOL + col] = (__bf16)val;
        }
      } else if constexpr (MODE == 2) {
        __bf16* O = (__bf16*)outp;
        const int bb = mbase >> 11;
        const int tok = mbase & 2047;
        bf16x4 pk;
#pragma unroll
        for (int r = 0; r < 4; ++r) pk[r] = (__bf16)acc[i][j][r];
        *(bf16x4*)(O + ((size_t)(bb * 1024 + col)) * 2048 + tok) = pk;
      } else {
        float* O = (float*)outp;
#pragma unroll
        for (int r = 0; r < 4; ++r)
          O[(size_t)(mbase + r) * NCOL + col] = acc[i][j][r];
      }
    }
  }
}

// ---------------------------------------------------------------- flash attention
// Q,K: bf16 token-major [b,s,h*64+d]; Q pre-scaled by 0.125*log2(e) (exp2 units).
// Vt:  bf16 [b*1024 + h*64 + d][s].
// U:   bf16 token-major [b,s,h*64+d].
//
// SWAPPED-OPERAND structure: S^T = mfma(K, Q) so each lane owns ONE q-row
// (q = ln) with 16 kv values (kv = 16c + 4g + r). Row stats are lane-scalar;
// reduces are in-lane trees + 2 shfl_xor across the 4 g-lanes. PV runs
// swapped too (O^T = mfma(V^T, P^T)), so rescale/normalize stay lane-scalar.
// P goes through a tiny per-wave padded LDS buffer (4x ds_write_b64 +
// 2x ds_read_b128, conflict-free).
__global__ __launch_bounds__(512, 4)
void attn_fwd(const __bf16* __restrict__ Q, const __bf16* __restrict__ Kk,
              const __bf16* __restrict__ Vt, __bf16* __restrict__ U) {
  constexpr int S = 2048;
  __shared__ __align__(16) __bf16 Klds[2][2 * 64 * 32];  // [buf][dk-half][kv][32]
  __shared__ __align__(16) __bf16 Vlds[2][2 * 64 * 32];  // [buf][kv-half][d][32]
  __shared__ __align__(16) unsigned int Plds[8][16 * 36]; // per wave: [q][36 u32] (144B rows)

  const int t = threadIdx.x;
  const int lane = t & 63, wave = t >> 6;
  const int g = lane >> 4, ln = lane & 15;
  const int qt = blockIdx.x;             // 0..7
  const int bh = blockIdx.y;
  const int b = bh >> 4, h = bh & 15;
  const int q0s[2] = {qt * 128, (15 - qt) * 128};
  const int nts[2] = {2 * qt + 2, 32 - 2 * qt};   // nts[1] > nts[0] always

  // Q fragments (B-operand): lane holds Q[q=ln][k = s*32 + g*8 + j]
  bf16x8 qf[2][2];
#pragma unroll
  for (int s2 = 0; s2 < 2; ++s2) {
    const __bf16* Qb = Q + ((size_t)(b * S + q0s[s2] + wave * 16 + ln)) * 1024 + h * 64;
    qf[s2][0] = *(const bf16x8*)(Qb + g * 8);
    qf[s2][1] = *(const bf16x8*)(Qb + 32 + g * 8);
  }

  // O^T accumulator: o[s2][c2][r] = O^T[d = 16*c2 + 4g + r][q = ln]
  f32x4 o[2][4] = {};
  float mrow[2], lrow[2];
#pragma unroll
  for (int s2 = 0; s2 < 2; ++s2) { mrow[s2] = -3.0e38f; lrow[s2] = 0.f; }

  // staging: 512 threads cover one 8KB tile (4096 elems) per call
  const int half = t >> 8;          // 0,1
  const int srow = (t >> 2) & 63;   // 0..63
  const int scol = (t & 3) * 8;
  const __bf16* Kg = Kk + ((size_t)(b * S + srow)) * 1024 + h * 64 + half * 32 + scol;
  const __bf16* Vg = Vt + ((size_t)(b * 1024 + h * 64 + srow)) * 2048 + half * 32 + scol;
  const int nt = nts[1];

  // prologue: stage tile 0 into buf 0
  gload_lds16(Kg, (__bf16*)Klds[0] + t * 8);
  gload_lds16(Vg, (__bf16*)Vlds[0] + t * 8);
  __syncthreads();

  for (int kt = 0; kt < nt; ++kt) {
    const int cur = kt & 1;
    if (kt + 1 < nt) {  // prefetch next tile into other buffer (overlaps compute)
      const size_t kv1 = (size_t)(kt + 1) * 64;
      gload_lds16(Kg + kv1 * 1024, (__bf16*)Klds[cur ^ 1] + t * 8);
      gload_lds16(Vg + kv1, (__bf16*)Vlds[cur ^ 1] + t * 8);
    }
    const int kv0 = kt * 64;

#pragma unroll
    for (int s2 = 0; s2 < 2; ++s2) {
      if (kt >= nts[s2]) continue;  // block-uniform branch

      // S^T = K Q^T : sa[c][r] = S[kv = kv0+16c+4g+r][q = ln]
      f32x4 sa[4] = {};
      __builtin_amdgcn_s_setprio(1);
#pragma unroll
      for (int s = 0; s < 2; ++s) {
#pragma unroll
        for (int c = 0; c < 4; ++c) {
          bf16x8 kf = *(const bf16x8*)(Klds[cur] + s * 2048 + (c * 16 + ln) * 32 + g * 8);
          sa[c] = mfma_bf16(kf, qf[s2][s], sa[c]);
        }
      }
      __builtin_amdgcn_s_setprio(0);

      const int rfbase = q0s[s2] + wave * 16;
      const int rq = rfbase + ln;  // this lane's q-row
      if (kv0 + 63 > rfbase) {     // causal mask (only near the diagonal)
#pragma unroll
        for (int c = 0; c < 4; ++c)
#pragma unroll
          for (int r = 0; r < 4; ++r)
            if (kv0 + c * 16 + g * 4 + r > rq) sa[c][r] = -1e30f;
      }

      // ---- online softmax, lane-scalar row state (exp2 units) ----
      float tm[8];
#pragma unroll
      for (int i = 0; i < 8; ++i) tm[i] = fmaxf(sa[i >> 2][i & 3], sa[2 + (i >> 2)][i & 3]);
#pragma unroll
      for (int st = 4; st >= 1; st >>= 1)
#pragma unroll
        for (int i = 0; i < st; ++i) tm[i] = fmaxf(tm[i], tm[i + st]);
      float pm = tm[0];  // in-lane max of this lane's 16 values

      if (__any(pm > mrow[s2] + 8.f)) {  // defer-max gate
        pm = fmaxf(pm, __shfl_xor(pm, 16));
        pm = fmaxf(pm, __shfl_xor(pm, 32));
        const float mn = fmaxf(mrow[s2], pm);
        const float alpha = exp2f(mrow[s2] - mn);
        mrow[s2] = mn;
        lrow[s2] *= alpha;
#pragma unroll
        for (int c2 = 0; c2 < 4; ++c2)
#pragma unroll
          for (int r = 0; r < 4; ++r) o[s2][c2][r] *= alpha;
      }

      float p[4][4];
#pragma unroll
      for (int c = 0; c < 4; ++c)
#pragma unroll
        for (int r = 0; r < 4; ++r) p[c][r] = exp2f(sa[c][r] - mrow[s2]);

      float ts[8];
#pragma unroll
      for (int i = 0; i < 8; ++i) ts[i] = p[i >> 2][i & 3] + p[2 + (i >> 2)][i & 3];
#pragma unroll
      for (int st = 4; st >= 1; st >>= 1)
#pragma unroll
        for (int i = 0; i < st; ++i) ts[i] += ts[i + st];
      float rs = ts[0];
      rs += __shfl_xor(rs, 16);
      rs += __shfl_xor(rs, 32);
      lrow[s2] += rs;

      // pack P^T rows: lane writes its (q=ln) row's kv pairs {16c+4g, +1..+3}
      unsigned int* Pw = Plds[wave] + ln * 36;
#pragma unroll
      for (int c = 0; c < 4; ++c) {
        u32x2 w;
        w[0] = pk_bf16(p[c][0], p[c][1]);
        w[1] = pk_bf16(p[c][2], p[c][3]);
        *(u32x2*)(Pw + 8 * c + 2 * g) = w;
      }

      // O^T += V^T P^T  (A = V^T tile, B = P^T from per-wave LDS; wave-local)
      __builtin_amdgcn_s_setprio(1);
#pragma unroll
      for (int sh = 0; sh < 2; ++sh) {
        bf16x8 pb = *(const bf16x8*)((const __bf16*)(Plds[wave]) + ln * 72 + sh * 32 + g * 8);
#pragma unroll
        for (int c2 = 0; c2 < 4; ++c2) {
          bf16x8 vf = *(const bf16x8*)(Vlds[cur] + sh * 2048 + (c2 * 16 + ln) * 32 + g * 8);
          o[s2][c2] = mfma_bf16(vf, pb, o[s2][c2]);
        }
      }
      __builtin_amdgcn_s_setprio(0);
    }
    __syncthreads();  // drains prefetch vmcnt + protects buffer swap
  }

  // normalize + write U (token-major); lane owns q-row ln, d = 16c2+4g+r
#pragma unroll
  for (int s2 = 0; s2 < 2; ++s2) {
    const float rl = 1.0f / lrow[s2];
    __bf16* Ub = U + ((size_t)(b * S + q0s[s2] + wave * 16 + ln)) * 1024 + h * 64;
#pragma unroll
    for (int c2 = 0; c2 < 4; ++c2) {
      bf16x4 pk4;
#pragma unroll
      for (int r = 0; r < 4; ++r) pk4[r] = (__bf16)(o[s2][c2][r] * rl);
      *(bf16x4*)(Ub + 16 * c2 + 4 * g) = pk4;
    }
  }
}

// ---------------------------------------------------------------- launch
extern "C" void kernel_launch(void* const* d_in, const int* in_sizes, int n_in,
                              void* d_out, int out_size, void* d_ws, size_t ws_size,
                              hipStream_t stream) {
  const float* x    = (const float*)d_in[0];
  const float* fcos = (const float*)d_in[1];
  const float* fsin = (const float*)d_in[2];
  const float* Wq   = (const float*)d_in[3];
  const float* Wk   = (const float*)d_in[4];
  const float* Wv   = (const float*)d_in[5];
  const float* Wo   = (const float*)d_in[6];

  char* ws = (char*)d_ws;
  __bf16* xb  = (__bf16*)(ws);                       // 16 MB: x as bf16 (8192x1024)
  __bf16* Wqb = (__bf16*)(ws + (16u << 20));         // 2 MB each
  __bf16* Wkb = (__bf16*)(ws + (18u << 20));
  __bf16* Wvb = (__bf16*)(ws + (20u << 20));
  __bf16* Wob = (__bf16*)(ws + (22u << 20));
  __bf16* Qb  = (__bf16*)(ws + (24u << 20));         // 16 MB
  __bf16* Kb  = (__bf16*)(ws + (40u << 20));         // 16 MB
  __bf16* Vtb = (__bf16*)(ws + (56u << 20));         // 16 MB (ends at 72 MB)
  __bf16* Ub  = xb;  // x no longer needed after V projection

  cvt_bf16<<<8192, 256, 0, stream>>>(x,  xb,  8192 * 1024 / 4);
  cvt_bf16<<<1024, 256, 0, stream>>>(Wq, Wqb, 1024 * 1024 / 4);
  cvt_bf16<<<1024, 256, 0, stream>>>(Wk, Wkb, 1024 * 1024 / 4);
  cvt_bf16<<<1024, 256, 0, stream>>>(Wv, Wvb, 1024 * 1024 / 4);
  cvt_bf16<<<1024, 256, 0, stream>>>(Wo, Wob, 1024 * 1024 / 4);

  dim3 gg(8, 64);
  gemm_bt<0><<<gg, 256, 0, stream>>>(xb, Wqb, Qb,  fcos, fsin);
  gemm_bt<1><<<gg, 256, 0, stream>>>(xb, Wkb, Kb,  fcos, fsin);
  gemm_bt<2><<<gg, 256, 0, stream>>>(xb, Wvb, Vtb, nullptr, nullptr);
  attn_fwd<<<dim3(8, 64), 512, 0, stream>>>(Qb, Kb, Vtb, Ub);
  gemm_bt<3><<<gg, 256, 0, stream>>>(Ub, Wob, d_out, nullptr, nullptr);
}

// Round 6
// 216.880 us; speedup vs baseline: 1.6118x; 1.0426x over previous
//
#include <hip/hip_runtime.h>
#include <hip/hip_bf16.h>

typedef __attribute__((ext_vector_type(8))) __bf16 bf16x8;
typedef __attribute__((ext_vector_type(4))) __bf16 bf16x4;
typedef __attribute__((ext_vector_type(4))) float f32x4;
typedef __attribute__((ext_vector_type(2))) unsigned int u32x2;

static __device__ __forceinline__ f32x4 mfma_bf16(bf16x8 a, bf16x8 b, f32x4 c) {
  return __builtin_amdgcn_mfma_f32_16x16x32_bf16(a, b, c, 0, 0, 0);
}

// async global->LDS, 16B per lane. LDS dest must be linear in lane order.
static __device__ __forceinline__ void gload_lds16(const void* g, void* l) {
  __builtin_amdgcn_global_load_lds(
      (__attribute__((address_space(1))) unsigned int*)g,
      (__attribute__((address_space(3))) unsigned int*)l, 16, 0, 0);
}

static __device__ __forceinline__ unsigned int pk_bf16(float a, float b) {
  union { __bf16 h; unsigned short u; } x, y;
  x.h = (__bf16)a; y.h = (__bf16)b;
  return ((unsigned int)y.u << 16) | x.u;
}

// ---------------------------------------------------------------- fp32 -> bf16
__global__ void cvt_bf16(const float* __restrict__ in, __bf16* __restrict__ out, int n4) {
  int i = blockIdx.x * blockDim.x + threadIdx.x;
  if (i >= n4) return;
  f32x4 v = ((const f32x4*)in)[i];
  bf16x4 o;
#pragma unroll
  for (int k = 0; k < 4; ++k) o[k] = (__bf16)v[k];
  ((bf16x4*)out)[i] = o;
}

// ---------------------------------------------------------------- GEMM  C = A @ W^T
// 256x128 tile, BK=64, 8 waves (2M x 4N), per-wave 128x32.
// A staged 3-deep, B 2-deep, counted vmcnt(4) at tile entry (never 0 in loop).
// LDS tiles XOR-swizzled (byte ^= (row&7)<<4) via pre-swizzled global source
// (linear gload_lds dest) + same XOR on ds_read.
// MODE 0: Q -> rope + *0.125*log2(e); MODE 1: K -> rope; MODE 2: V transposed
// [b*1024+n][tok]; MODE 3: fp32 out.
template <int MODE>
__global__ __launch_bounds__(512, 1)
void gemm256(const __bf16* __restrict__ A, const __bf16* __restrict__ W,
             void* __restrict__ outp,
             const float* __restrict__ fcos, const float* __restrict__ fsin) {
  constexpr int K = 1024;
  constexpr int NT = K / 64;  // 16 K-tiles
  extern __shared__ __align__(16) __bf16 dynlds[];
  __bf16* Al = dynlds;            // 3 slots x 16384 elems (256x64)
  __bf16* Bl = dynlds + 49152;    // 2 slots x  8192 elems (128x64)

  const int t = threadIdx.x;
  const int lane = t & 63, wave = t >> 6;
  const int g = lane >> 4, ln = lane & 15;
  const int wm = wave >> 2, wn = wave & 3;  // 2 x 4 waves -> per-wave 128x32
  const int bn = blockIdx.x, bm = blockIdx.y;

  f32x4 acc[8][2] = {};

  // ---- staging addressing (pre-swizzled source) ----
  const int srow8 = t >> 3;                                   // 0..63 (+c*64)
  const int scole = (((t & 7) ^ ((t >> 3) & 7)) << 3);        // swizzled elem col
  const __bf16* Ag = A + (size_t)(bm * 256 + srow8) * K + scole;
  const __bf16* Wg = W + (size_t)(bn * 128 + srow8) * K + scole;

#define ISSUE_A(kt, slot)                                                   \
  {                                                                         \
    const int k0 = (kt) * 64;                                               \
    __bf16* d = Al + (slot) * 16384 + t * 8;                                \
    gload_lds16(Ag + k0, d);                                                \
    gload_lds16(Ag + (size_t)64 * K + k0, d + 4096);                        \
    gload_lds16(Ag + (size_t)128 * K + k0, d + 8192);                       \
    gload_lds16(Ag + (size_t)192 * K + k0, d + 12288);                      \
  }
#define ISSUE_B(kt, slot)                                                   \
  {                                                                         \
    const int k0 = (kt) * 64;                                               \
    __bf16* d = Bl + (slot) * 8192 + t * 8;                                 \
    gload_lds16(Wg + k0, d);                                                \
    gload_lds16(Wg + (size_t)64 * K + k0, d + 4096);                        \
  }

  // ---- fragment read addressing (swizzled) ----
  // elem offset = row*64 + (((s<<2)|g) ^ (ln&7))*8
  const int axr = ln & 7;
  int aoff[8], boff[2];
#pragma unroll
  for (int i = 0; i < 8; ++i) aoff[i] = (wm * 128 + i * 16 + ln) * 64;
#pragma unroll
  for (int j = 0; j < 2; ++j) boff[j] = (wn * 32 + j * 16 + ln) * 64;

  // prologue: A(0), B(0), A(1)
  ISSUE_A(0, 0);
  ISSUE_B(0, 0);
  ISSUE_A(1, 1);

#define TILE_BODY(tt, LAST)                                                 \
  {                                                                         \
    if (LAST) { asm volatile("s_waitcnt vmcnt(0)" ::: "memory"); }          \
    else      { asm volatile("s_waitcnt vmcnt(4)" ::: "memory"); }          \
    __builtin_amdgcn_s_barrier();                                           \
    __builtin_amdgcn_sched_barrier(0);                                      \
    const __bf16* Ab = Al + ((tt) % 3) * 16384;                             \
    const __bf16* Bb = Bl + ((tt) & 1) * 8192;                              \
    bf16x8 af[8], bf[2];                                                    \
    /* slice 0 */                                                           \
    _Pragma("unroll") for (int i = 0; i < 8; ++i)                           \
      af[i] = *(const bf16x8*)(Ab + aoff[i] + ((g ^ axr) << 3));            \
    _Pragma("unroll") for (int j = 0; j < 2; ++j)                           \
      bf[j] = *(const bf16x8*)(Bb + boff[j] + ((g ^ axr) << 3));            \
    if (!(LAST)) ISSUE_B((tt) + 1, ((tt) + 1) & 1);                         \
    __builtin_amdgcn_s_setprio(1);                                          \
    _Pragma("unroll") for (int i = 0; i < 8; ++i)                           \
      _Pragma("unroll") for (int j = 0; j < 2; ++j)                         \
        acc[i][j] = mfma_bf16(af[i], bf[j], acc[i][j]);                     \
    __builtin_amdgcn_s_setprio(0);                                          \
    /* slice 1 */                                                           \
    _Pragma("unroll") for (int i = 0; i < 8; ++i)                           \
      af[i] = *(const bf16x8*)(Ab + aoff[i] + (((4 | g) ^ axr) << 3));      \
    _Pragma("unroll") for (int j = 0; j < 2; ++j)                           \
      bf[j] = *(const bf16x8*)(Bb + boff[j] + (((4 | g) ^ axr) << 3));      \
    if ((tt) + 2 < NT) ISSUE_A((tt) + 2, ((tt) + 2) % 3);                   \
    __builtin_amdgcn_s_setprio(1);                                          \
    _Pragma("unroll") for (int i = 0; i < 8; ++i)                           \
      _Pragma("unroll") for (int j = 0; j < 2; ++j)                         \
        acc[i][j] = mfma_bf16(af[i], bf[j], acc[i][j]);                     \
    __builtin_amdgcn_s_setprio(0);                                          \
  }

  for (int tt = 0; tt < NT - 1; ++tt) TILE_BODY(tt, false);
  TILE_BODY(NT - 1, true);
#undef TILE_BODY
#undef ISSUE_A
#undef ISSUE_B

  // ---- epilogue. D-layout: col=ln, row=g*4+r within each 16x16 frag ----
#pragma unroll
  for (int i = 0; i < 8; ++i) {
    const int mbase = bm * 256 + wm * 128 + i * 16 + g * 4;
#pragma unroll
    for (int j = 0; j < 2; ++j) {
      const int col = bn * 128 + wn * 32 + j * 16 + ln;
      if constexpr (MODE == 0 || MODE == 1) {
        const int fi = (col & 63) >> 1;
        const bool odd = (col & 1) != 0;
        __bf16* O = (__bf16*)outp;
#pragma unroll
        for (int r = 0; r < 4; ++r) {
          const int row = mbase + r;
          const int tok = row & 2047;
          const float cs = fcos[tok * 32 + fi];
          const float sn = fsin[tok * 32 + fi];
          const float own = acc[i][j][r];
          const float oth = __shfl_xor(own, 1);  // partner column d^1
          float val = own * cs + (odd ? oth * sn : -oth * sn);
          if constexpr (MODE == 0) val *= 0.1803368802f;  // 0.125 * log2(e)
          O[(size_t)row * 1024 + col] = (__bf16)val;
        }
      } else if constexpr (MODE == 2) {
        __bf16* O = (__bf16*)outp;
        const int bb = mbase >> 11;
        const int tok = mbase & 2047;
        bf16x4 pk;
#pragma unroll
        for (int r = 0; r < 4; ++r) pk[r] = (__bf16)acc[i][j][r];
        *(bf16x4*)(O + ((size_t)(bb * 1024 + col)) * 2048 + tok) = pk;
      } else {
        float* O = (float*)outp;
#pragma unroll
        for (int r = 0; r < 4; ++r)
          O[(size_t)(mbase + r) * 1024 + col] = acc[i][j][r];
      }
    }
  }
}

// ---------------------------------------------------------------- flash attention
// (unchanged from round 5 -- swapped-operand, paired strips, 512 threads)
__global__ __launch_bounds__(512, 4)
void attn_fwd(const __bf16* __restrict__ Q, const __bf16* __restrict__ Kk,
              const __bf16* __restrict__ Vt, __bf16* __restrict__ U) {
  constexpr int S = 2048;
  __shared__ __align__(16) __bf16 Klds[2][2 * 64 * 32];
  __shared__ __align__(16) __bf16 Vlds[2][2 * 64 * 32];
  __shared__ __align__(16) unsigned int Plds[8][16 * 36];

  const int t = threadIdx.x;
  const int lane = t & 63, wave = t >> 6;
  const int g = lane >> 4, ln = lane & 15;
  const int qt = blockIdx.x;
  const int bh = blockIdx.y;
  const int b = bh >> 4, h = bh & 15;
  const int q0s[2] = {qt * 128, (15 - qt) * 128};
  const int nts[2] = {2 * qt + 2, 32 - 2 * qt};

  bf16x8 qf[2][2];
#pragma unroll
  for (int s2 = 0; s2 < 2; ++s2) {
    const __bf16* Qb = Q + ((size_t)(b * S + q0s[s2] + wave * 16 + ln)) * 1024 + h * 64;
    qf[s2][0] = *(const bf16x8*)(Qb + g * 8);
    qf[s2][1] = *(const bf16x8*)(Qb + 32 + g * 8);
  }

  f32x4 o[2][4] = {};
  float mrow[2], lrow[2];
#pragma unroll
  for (int s2 = 0; s2 < 2; ++s2) { mrow[s2] = -3.0e38f; lrow[s2] = 0.f; }

  const int half = t >> 8;
  const int srow = (t >> 2) & 63;
  const int scol = (t & 3) * 8;
  const __bf16* Kg = Kk + ((size_t)(b * S + srow)) * 1024 + h * 64 + half * 32 + scol;
  const __bf16* Vg = Vt + ((size_t)(b * 1024 + h * 64 + srow)) * 2048 + half * 32 + scol;
  const int nt = nts[1];

  gload_lds16(Kg, (__bf16*)Klds[0] + t * 8);
  gload_lds16(Vg, (__bf16*)Vlds[0] + t * 8);
  __syncthreads();

  for (int kt = 0; kt < nt; ++kt) {
    const int cur = kt & 1;
    if (kt + 1 < nt) {
      const size_t kv1 = (size_t)(kt + 1) * 64;
      gload_lds16(Kg + kv1 * 1024, (__bf16*)Klds[cur ^ 1] + t * 8);
      gload_lds16(Vg + kv1, (__bf16*)Vlds[cur ^ 1] + t * 8);
    }
    const int kv0 = kt * 64;

#pragma unroll
    for (int s2 = 0; s2 < 2; ++s2) {
      if (kt >= nts[s2]) continue;

      f32x4 sa[4] = {};
      __builtin_amdgcn_s_setprio(1);
#pragma unroll
      for (int s = 0; s < 2; ++s) {
#pragma unroll
        for (int c = 0; c < 4; ++c) {
          bf16x8 kf = *(const bf16x8*)(Klds[cur] + s * 2048 + (c * 16 + ln) * 32 + g * 8);
          sa[c] = mfma_bf16(kf, qf[s2][s], sa[c]);
        }
      }
      __builtin_amdgcn_s_setprio(0);

      const int rfbase = q0s[s2] + wave * 16;
      const int rq = rfbase + ln;
      if (kv0 + 63 > rfbase) {
#pragma unroll
        for (int c = 0; c < 4; ++c)
#pragma unroll
          for (int r = 0; r < 4; ++r)
            if (kv0 + c * 16 + g * 4 + r > rq) sa[c][r] = -1e30f;
      }

      float tm[8];
#pragma unroll
      for (int i = 0; i < 8; ++i) tm[i] = fmaxf(sa[i >> 2][i & 3], sa[2 + (i >> 2)][i & 3]);
#pragma unroll
      for (int st = 4; st >= 1; st >>= 1)
#pragma unroll
        for (int i = 0; i < st; ++i) tm[i] = fmaxf(tm[i], tm[i + st]);
      float pm = tm[0];

      if (__any(pm > mrow[s2] + 8.f)) {
        pm = fmaxf(pm, __shfl_xor(pm, 16));
        pm = fmaxf(pm, __shfl_xor(pm, 32));
        const float mn = fmaxf(mrow[s2], pm);
        const float alpha = exp2f(mrow[s2] - mn);
        mrow[s2] = mn;
        lrow[s2] *= alpha;
#pragma unroll
        for (int c2 = 0; c2 < 4; ++c2)
#pragma unroll
          for (int r = 0; r < 4; ++r) o[s2][c2][r] *= alpha;
      }

      float p[4][4];
#pragma unroll
      for (int c = 0; c < 4; ++c)
#pragma unroll
        for (int r = 0; r < 4; ++r) p[c][r] = exp2f(sa[c][r] - mrow[s2]);

      float ts[8];
#pragma unroll
      for (int i = 0; i < 8; ++i) ts[i] = p[i >> 2][i & 3] + p[2 + (i >> 2)][i & 3];
#pragma unroll
      for (int st = 4; st >= 1; st >>= 1)
#pragma unroll
        for (int i = 0; i < st; ++i) ts[i] += ts[i + st];
      float rs = ts[0];
      rs += __shfl_xor(rs, 16);
      rs += __shfl_xor(rs, 32);
      lrow[s2] += rs;

      unsigned int* Pw = Plds[wave] + ln * 36;
#pragma unroll
      for (int c = 0; c < 4; ++c) {
        u32x2 w;
        w[0] = pk_bf16(p[c][0], p[c][1]);
        w[1] = pk_bf16(p[c][2], p[c][3]);
        *(u32x2*)(Pw + 8 * c + 2 * g) = w;
      }

      __builtin_amdgcn_s_setprio(1);
#pragma unroll
      for (int sh = 0; sh < 2; ++sh) {
        bf16x8 pb = *(const bf16x8*)((const __bf16*)(Plds[wave]) + ln * 72 + sh * 32 + g * 8);
#pragma unroll
        for (int c2 = 0; c2 < 4; ++c2) {
          bf16x8 vf = *(const bf16x8*)(Vlds[cur] + sh * 2048 + (c2 * 16 + ln) * 32 + g * 8);
          o[s2][c2] = mfma_bf16(vf, pb, o[s2][c2]);
        }
      }
      __builtin_amdgcn_s_setprio(0);
    }
    __syncthreads();
  }

#pragma unroll
  for (int s2 = 0; s2 < 2; ++s2) {
    const float rl = 1.0f / lrow[s2];
    __bf16* Ub = U + ((size_t)(b * S + q0s[s2] + wave * 16 + ln)) * 1024 + h * 64;
#pragma unroll
    for (int c2 = 0; c2 < 4; ++c2) {
      bf16x4 pk4;
#pragma unroll
      for (int r = 0; r < 4; ++r) pk4[r] = (__bf16)(o[s2][c2][r] * rl);
      *(bf16x4*)(Ub + 16 * c2 + 4 * g) = pk4;
    }
  }
}

// ---------------------------------------------------------------- launch
extern "C" void kernel_launch(void* const* d_in, const int* in_sizes, int n_in,
                              void* d_out, int out_size, void* d_ws, size_t ws_size,
                              hipStream_t stream) {
  const float* x    = (const float*)d_in[0];
  const float* fcos = (const float*)d_in[1];
  const float* fsin = (const float*)d_in[2];
  const float* Wq   = (const float*)d_in[3];
  const float* Wk   = (const float*)d_in[4];
  const float* Wv   = (const float*)d_in[5];
  const float* Wo   = (const float*)d_in[6];

  char* ws = (char*)d_ws;
  __bf16* xb  = (__bf16*)(ws);                       // 16 MB
  __bf16* Wqb = (__bf16*)(ws + (16u << 20));         // 2 MB each
  __bf16* Wkb = (__bf16*)(ws + (18u << 20));
  __bf16* Wvb = (__bf16*)(ws + (20u << 20));
  __bf16* Wob = (__bf16*)(ws + (22u << 20));
  __bf16* Qb  = (__bf16*)(ws + (24u << 20));         // 16 MB
  __bf16* Kb  = (__bf16*)(ws + (40u << 20));         // 16 MB
  __bf16* Vtb = (__bf16*)(ws + (56u << 20));         // 16 MB (ends at 72 MB)
  __bf16* Ub  = xb;

  cvt_bf16<<<8192, 256, 0, stream>>>(x,  xb,  8192 * 1024 / 4);
  cvt_bf16<<<1024, 256, 0, stream>>>(Wq, Wqb, 1024 * 1024 / 4);
  cvt_bf16<<<1024, 256, 0, stream>>>(Wk, Wkb, 1024 * 1024 / 4);
  cvt_bf16<<<1024, 256, 0, stream>>>(Wv, Wvb, 1024 * 1024 / 4);
  cvt_bf16<<<1024, 256, 0, stream>>>(Wo, Wob, 1024 * 1024 / 4);

  dim3 gg(8, 32);  // (bn, bm): 256 blocks = 1/CU
  const size_t lds = 131072;
  gemm256<0><<<gg, 512, lds, stream>>>(xb, Wqb, Qb,  fcos, fsin);
  gemm256<1><<<gg, 512, lds, stream>>>(xb, Wkb, Kb,  fcos, fsin);
  gemm256<2><<<gg, 512, lds, stream>>>(xb, Wvb, Vtb, nullptr, nullptr);
  attn_fwd<<<dim3(8, 64), 512, 0, stream>>>(Qb, Kb, Vtb, Ub);
  gemm256<3><<<gg, 512, lds, stream>>>(Ub, Wob, d_out, nullptr, nullptr);
}

// Round 8
// 210.507 us; speedup vs baseline: 1.6605x; 1.0303x over previous
//
#include <hip/hip_runtime.h>
#include <hip/hip_bf16.h>

typedef __attribute__((ext_vector_type(8))) __bf16 bf16x8;
typedef __attribute__((ext_vector_type(4))) __bf16 bf16x4;
typedef __attribute__((ext_vector_type(4))) float f32x4;
typedef __attribute__((ext_vector_type(2))) unsigned int u32x2;

static __device__ __forceinline__ f32x4 mfma_bf16(bf16x8 a, bf16x8 b, f32x4 c) {
  return __builtin_amdgcn_mfma_f32_16x16x32_bf16(a, b, c, 0, 0, 0);
}

// async global->LDS, 16B per lane. LDS dest must be linear in lane order.
static __device__ __forceinline__ void gload_lds16(const void* g, void* l) {
  __builtin_amdgcn_global_load_lds(
      (__attribute__((address_space(1))) unsigned int*)g,
      (__attribute__((address_space(3))) unsigned int*)l, 16, 0, 0);
}

static __device__ __forceinline__ unsigned int pk_bf16(float a, float b) {
  union { __bf16 h; unsigned short u; } x, y;
  x.h = (__bf16)a; y.h = (__bf16)b;
  return ((unsigned int)y.u << 16) | x.u;
}

// ---------------------------------------------------------------- fp32 -> bf16
__global__ void cvt_bf16(const float* __restrict__ in, __bf16* __restrict__ out, int n4) {
  int i = blockIdx.x * blockDim.x + threadIdx.x;
  if (i >= n4) return;
  f32x4 v = ((const f32x4*)in)[i];
  bf16x4 o;
#pragma unroll
  for (int k = 0; k < 4; ++k) o[k] = (__bf16)v[k];
  ((bf16x4*)out)[i] = o;
}

// 4 weight matrices in one launch (1024x1024 each)
__global__ void cvt_w4(const float* __restrict__ w0, const float* __restrict__ w1,
                       const float* __restrict__ w2, const float* __restrict__ w3,
                       __bf16* __restrict__ o0, __bf16* __restrict__ o1,
                       __bf16* __restrict__ o2, __bf16* __restrict__ o3) {
  const float* in; __bf16* out;
  switch (blockIdx.y) {
    case 0: in = w0; out = o0; break;
    case 1: in = w1; out = o1; break;
    case 2: in = w2; out = o2; break;
    default: in = w3; out = o3; break;
  }
  int i = blockIdx.x * blockDim.x + threadIdx.x;
  f32x4 v = ((const f32x4*)in)[i];
  bf16x4 o;
#pragma unroll
  for (int k = 0; k < 4; ++k) o[k] = (__bf16)v[k];
  ((bf16x4*)out)[i] = o;
}

// ---------------------------------------------------------------- GEMM  C = A @ W^T
// 256x128 tile, BK=64, 8 waves as 4M x 2N (64x64 per wave).
// 2 phases/K-tile: {ds_read slice; [stage-issue | counted vmcnt]; barrier;
// lgkmcnt(0); sched_barrier; setprio; 16 MFMA; barrier}.
// CORRECTNESS INVARIANT (R7 bug): a tile's LDS may only be ds_read after
// EVERY wave's vmcnt wait for that tile's staging has been followed by a
// block barrier. Hence the vmcnt(4) for tile t+1's data sits in tile t's
// phase 1, before that phase's barrier. vmcnt(4) leaves A(t+2) in flight
// (never drains to 0 in steady state).
// A 3-slot + B 2-slot = 128 KB dynamic LDS. XOR-swizzle via pre-swizzled
// global source (linear gload dest) + same XOR on ds_read.
// MODE 0: Q -> rope + *0.125*log2(e); MODE 1: K -> rope; MODE 2: V transposed
// [b*1024+n][tok]; MODE 3: fp32 out.
template <int MODE>
__global__ __launch_bounds__(512, 1)
void gemm256(const __bf16* __restrict__ A, const __bf16* __restrict__ W,
             void* __restrict__ outp,
             const float* __restrict__ fcos, const float* __restrict__ fsin) {
  constexpr int K = 1024;
  constexpr int NT = K / 64;  // 16 K-tiles
  extern __shared__ __align__(16) __bf16 dynlds[];
  __bf16* Al = dynlds;            // 3 slots x 16384 elems (256x64)
  __bf16* Bl = dynlds + 49152;    // 2 slots x  8192 elems (128x64)

  const int t = threadIdx.x;
  const int lane = t & 63, wave = t >> 6;
  const int g = lane >> 4, ln = lane & 15;
  const int wm = wave >> 1, wn = wave & 1;  // 4M x 2N -> per-wave 64x64
  const int bn = blockIdx.x, bm = blockIdx.y;

  f32x4 acc[4][4] = {};

  // ---- staging addressing (pre-swizzled source) ----
  const int srow8 = t >> 3;                                   // 0..63 (+c*64)
  const int scole = (((t & 7) ^ ((t >> 3) & 7)) << 3);        // swizzled elem col
  const __bf16* Ag = A + (size_t)(bm * 256 + srow8) * K + scole;
  const __bf16* Wg = W + (size_t)(bn * 128 + srow8) * K + scole;

#define ISSUE_A(kt, slot)                                                   \
  {                                                                         \
    const int k0 = (kt) * 64;                                               \
    __bf16* d = Al + (slot) * 16384 + t * 8;                                \
    gload_lds16(Ag + k0, d);                                                \
    gload_lds16(Ag + (size_t)64 * K + k0, d + 4096);                        \
    gload_lds16(Ag + (size_t)128 * K + k0, d + 8192);                       \
    gload_lds16(Ag + (size_t)192 * K + k0, d + 12288);                      \
  }
#define ISSUE_B(kt, slot)                                                   \
  {                                                                         \
    const int k0 = (kt) * 64;                                               \
    __bf16* d = Bl + (slot) * 8192 + t * 8;                                 \
    gload_lds16(Wg + k0, d);                                                \
    gload_lds16(Wg + (size_t)64 * K + k0, d + 4096);                        \
  }

  // ---- fragment read addressing (swizzled) ----
  const int axr = ln & 7;
  int aoff[4], boff[4];
#pragma unroll
  for (int i = 0; i < 4; ++i) aoff[i] = (wm * 64 + i * 16 + ln) * 64;
#pragma unroll
  for (int j = 0; j < 4; ++j) boff[j] = (wn * 64 + j * 16 + ln) * 64;

  // prologue: B(0), A(0), A(1); publish tile 0
  ISSUE_B(0, 0);
  ISSUE_A(0, 0);
  ISSUE_A(1, 1);
  asm volatile("s_waitcnt vmcnt(4)" ::: "memory");  // B0+A0 done, A1 in flight
  __builtin_amdgcn_s_barrier();

  int sa = 0;  // A slot of current tile (tt % 3)
  for (int tt = 0; tt < NT; ++tt) {
    const __bf16* Ab = Al + sa * 16384;
    const __bf16* Bb = Bl + (tt & 1) * 8192;
    bf16x8 af[4], bf[4];

    // ---------------- phase 0 : k-slice 0 (tile tt published) ----------------
#pragma unroll
    for (int i = 0; i < 4; ++i)
      af[i] = *(const bf16x8*)(Ab + aoff[i] + ((g ^ axr) << 3));
#pragma unroll
    for (int j = 0; j < 4; ++j)
      bf[j] = *(const bf16x8*)(Bb + boff[j] + ((g ^ axr) << 3));
    if (tt + 1 < NT) ISSUE_B(tt + 1, (tt + 1) & 1);
    if (tt + 2 < NT) ISSUE_A(tt + 2, sa == 0 ? 2 : sa - 1);  // (tt+2)%3
    __builtin_amdgcn_s_barrier();
    asm volatile("s_waitcnt lgkmcnt(0)" ::: "memory");
    __builtin_amdgcn_sched_barrier(0);
    __builtin_amdgcn_s_setprio(1);
#pragma unroll
    for (int i = 0; i < 4; ++i)
#pragma unroll
      for (int j = 0; j < 4; ++j)
        acc[i][j] = mfma_bf16(af[i], bf[j], acc[i][j]);
    __builtin_amdgcn_s_setprio(0);
    __builtin_amdgcn_s_barrier();

    // ---------------- phase 1 : k-slice 1 + publish tile tt+1 ----------------
#pragma unroll
    for (int i = 0; i < 4; ++i)
      af[i] = *(const bf16x8*)(Ab + aoff[i] + (((4 | g) ^ axr) << 3));
#pragma unroll
    for (int j = 0; j < 4; ++j)
      bf[j] = *(const bf16x8*)(Bb + boff[j] + (((4 | g) ^ axr) << 3));
    if (tt < NT - 2) { asm volatile("s_waitcnt vmcnt(4)" ::: "memory"); }
    else             { asm volatile("s_waitcnt vmcnt(0)" ::: "memory"); }
    __builtin_amdgcn_s_barrier();
    asm volatile("s_waitcnt lgkmcnt(0)" ::: "memory");
    __builtin_amdgcn_sched_barrier(0);
    __builtin_amdgcn_s_setprio(1);
#pragma unroll
    for (int i = 0; i < 4; ++i)
#pragma unroll
      for (int j = 0; j < 4; ++j)
        acc[i][j] = mfma_bf16(af[i], bf[j], acc[i][j]);
    __builtin_amdgcn_s_setprio(0);
    __builtin_amdgcn_s_barrier();

    sa = (sa == 2) ? 0 : sa + 1;
  }
#undef ISSUE_A
#undef ISSUE_B

  // ---- epilogue. D-layout: col=ln, row=g*4+r within each 16x16 frag ----
#pragma unroll
  for (int i = 0; i < 4; ++i) {
    const int mbase = bm * 256 + wm * 64 + i * 16 + g * 4;
#pragma unroll
    for (int j = 0; j < 4; ++j) {
      const int col = bn * 128 + wn * 64 + j * 16 + ln;
      if constexpr (MODE == 0 || MODE == 1) {
        const int fi = (col & 63) >> 1;
        const bool odd = (col & 1) != 0;
        __bf16* O = (__bf16*)outp;
#pragma unroll
        for (int r = 0; r < 4; ++r) {
          const int row = mbase + r;
          const int tok = row & 2047;
          const float cs = fcos[tok * 32 + fi];
          const float sn = fsin[tok * 32 + fi];
          const float own = acc[i][j][r];
          const float oth = __shfl_xor(own, 1);  // partner column d^1
          float val = own * cs + (odd ? oth * sn : -oth * sn);
          if constexpr (MODE == 0) val *= 0.1803368802f;  // 0.125 * log2(e)
          O[(size_t)row * 1024 + col] = (__bf16)val;
        }
      } else if constexpr (MODE == 2) {
        __bf16* O = (__bf16*)outp;
        const int bb = mbase >> 11;
        const int tok = mbase & 2047;
        bf16x4 pk;
#pragma unroll
        for (int r = 0; r < 4; ++r) pk[r] = (__bf16)acc[i][j][r];
        *(bf16x4*)(O + ((size_t)(bb * 1024 + col)) * 2048 + tok) = pk;
      } else {
        float* O = (float*)outp;
#pragma unroll
        for (int r = 0; r < 4; ++r)
          O[(size_t)(mbase + r) * 1024 + col] = acc[i][j][r];
      }
    }
  }
}

// ---------------------------------------------------------------- flash attention
// (unchanged from round 5 -- swapped-operand, paired strips, 512 threads)
__global__ __launch_bounds__(512, 4)
void attn_fwd(const __bf16* __restrict__ Q, const __bf16* __restrict__ Kk,
              const __bf16* __restrict__ Vt, __bf16* __restrict__ U) {
  constexpr int S = 2048;
  __shared__ __align__(16) __bf16 Klds[2][2 * 64 * 32];
  __shared__ __align__(16) __bf16 Vlds[2][2 * 64 * 32];
  __shared__ __align__(16) unsigned int Plds[8][16 * 36];

  const int t = threadIdx.x;
  const int lane = t & 63, wave = t >> 6;
  const int g = lane >> 4, ln = lane & 15;
  const int qt = blockIdx.x;
  const int bh = blockIdx.y;
  const int b = bh >> 4, h = bh & 15;
  const int q0s[2] = {qt * 128, (15 - qt) * 128};
  const int nts[2] = {2 * qt + 2, 32 - 2 * qt};

  bf16x8 qf[2][2];
#pragma unroll
  for (int s2 = 0; s2 < 2; ++s2) {
    const __bf16* Qb = Q + ((size_t)(b * S + q0s[s2] + wave * 16 + ln)) * 1024 + h * 64;
    qf[s2][0] = *(const bf16x8*)(Qb + g * 8);
    qf[s2][1] = *(const bf16x8*)(Qb + 32 + g * 8);
  }

  f32x4 o[2][4] = {};
  float mrow[2], lrow[2];
#pragma unroll
  for (int s2 = 0; s2 < 2; ++s2) { mrow[s2] = -3.0e38f; lrow[s2] = 0.f; }

  const int half = t >> 8;
  const int srow = (t >> 2) & 63;
  const int scol = (t & 3) * 8;
  const __bf16* Kg = Kk + ((size_t)(b * S + srow)) * 1024 + h * 64 + half * 32 + scol;
  const __bf16* Vg = Vt + ((size_t)(b * 1024 + h * 64 + srow)) * 2048 + half * 32 + scol;
  const int nt = nts[1];

  gload_lds16(Kg, (__bf16*)Klds[0] + t * 8);
  gload_lds16(Vg, (__bf16*)Vlds[0] + t * 8);
  __syncthreads();

  for (int kt = 0; kt < nt; ++kt) {
    const int cur = kt & 1;
    if (kt + 1 < nt) {
      const size_t kv1 = (size_t)(kt + 1) * 64;
      gload_lds16(Kg + kv1 * 1024, (__bf16*)Klds[cur ^ 1] + t * 8);
      gload_lds16(Vg + kv1, (__bf16*)Vlds[cur ^ 1] + t * 8);
    }
    const int kv0 = kt * 64;

#pragma unroll
    for (int s2 = 0; s2 < 2; ++s2) {
      if (kt >= nts[s2]) continue;

      f32x4 sa[4] = {};
      __builtin_amdgcn_s_setprio(1);
#pragma unroll
      for (int s = 0; s < 2; ++s) {
#pragma unroll
        for (int c = 0; c < 4; ++c) {
          bf16x8 kf = *(const bf16x8*)(Klds[cur] + s * 2048 + (c * 16 + ln) * 32 + g * 8);
          sa[c] = mfma_bf16(kf, qf[s2][s], sa[c]);
        }
      }
      __builtin_amdgcn_s_setprio(0);

      const int rfbase = q0s[s2] + wave * 16;
      const int rq = rfbase + ln;
      if (kv0 + 63 > rfbase) {
#pragma unroll
        for (int c = 0; c < 4; ++c)
#pragma unroll
          for (int r = 0; r < 4; ++r)
            if (kv0 + c * 16 + g * 4 + r > rq) sa[c][r] = -1e30f;
      }

      float tm[8];
#pragma unroll
      for (int i = 0; i < 8; ++i) tm[i] = fmaxf(sa[i >> 2][i & 3], sa[2 + (i >> 2)][i & 3]);
#pragma unroll
      for (int st = 4; st >= 1; st >>= 1)
#pragma unroll
        for (int i = 0; i < st; ++i) tm[i] = fmaxf(tm[i], tm[i + st]);
      float pm = tm[0];

      if (__any(pm > mrow[s2] + 8.f)) {
        pm = fmaxf(pm, __shfl_xor(pm, 16));
        pm = fmaxf(pm, __shfl_xor(pm, 32));
        const float mn = fmaxf(mrow[s2], pm);
        const float alpha = exp2f(mrow[s2] - mn);
        mrow[s2] = mn;
        lrow[s2] *= alpha;
#pragma unroll
        for (int c2 = 0; c2 < 4; ++c2)
#pragma unroll
          for (int r = 0; r < 4; ++r) o[s2][c2][r] *= alpha;
      }

      float p[4][4];
#pragma unroll
      for (int c = 0; c < 4; ++c)
#pragma unroll
        for (int r = 0; r < 4; ++r) p[c][r] = exp2f(sa[c][r] - mrow[s2]);

      float ts[8];
#pragma unroll
      for (int i = 0; i < 8; ++i) ts[i] = p[i >> 2][i & 3] + p[2 + (i >> 2)][i & 3];
#pragma unroll
      for (int st = 4; st >= 1; st >>= 1)
#pragma unroll
        for (int i = 0; i < st; ++i) ts[i] += ts[i + st];
      float rs = ts[0];
      rs += __shfl_xor(rs, 16);
      rs += __shfl_xor(rs, 32);
      lrow[s2] += rs;

      unsigned int* Pw = Plds[wave] + ln * 36;
#pragma unroll
      for (int c = 0; c < 4; ++c) {
        u32x2 w;
        w[0] = pk_bf16(p[c][0], p[c][1]);
        w[1] = pk_bf16(p[c][2], p[c][3]);
        *(u32x2*)(Pw + 8 * c + 2 * g) = w;
      }

      __builtin_amdgcn_s_setprio(1);
#pragma unroll
      for (int sh = 0; sh < 2; ++sh) {
        bf16x8 pb = *(const bf16x8*)((const __bf16*)(Plds[wave]) + ln * 72 + sh * 32 + g * 8);
#pragma unroll
        for (int c2 = 0; c2 < 4; ++c2) {
          bf16x8 vf = *(const bf16x8*)(Vlds[cur] + sh * 2048 + (c2 * 16 + ln) * 32 + g * 8);
          o[s2][c2] = mfma_bf16(vf, pb, o[s2][c2]);
        }
      }
      __builtin_amdgcn_s_setprio(0);
    }
    __syncthreads();
  }

#pragma unroll
  for (int s2 = 0; s2 < 2; ++s2) {
    const float rl = 1.0f / lrow[s2];
    __bf16* Ub = U + ((size_t)(b * S + q0s[s2] + wave * 16 + ln)) * 1024 + h * 64;
#pragma unroll
    for (int c2 = 0; c2 < 4; ++c2) {
      bf16x4 pk4;
#pragma unroll
      for (int r = 0; r < 4; ++r) pk4[r] = (__bf16)(o[s2][c2][r] * rl);
      *(bf16x4*)(Ub + 16 * c2 + 4 * g) = pk4;
    }
  }
}

// ---------------------------------------------------------------- launch
extern "C" void kernel_launch(void* const* d_in, const int* in_sizes, int n_in,
                              void* d_out, int out_size, void* d_ws, size_t ws_size,
                              hipStream_t stream) {
  const float* x    = (const float*)d_in[0];
  const float* fcos = (const float*)d_in[1];
  const float* fsin = (const float*)d_in[2];
  const float* Wq   = (const float*)d_in[3];
  const float* Wk   = (const float*)d_in[4];
  const float* Wv   = (const float*)d_in[5];
  const float* Wo   = (const float*)d_in[6];

  char* ws = (char*)d_ws;
  __bf16* xb  = (__bf16*)(ws);                       // 16 MB
  __bf16* Wqb = (__bf16*)(ws + (16u << 20));         // 2 MB each
  __bf16* Wkb = (__bf16*)(ws + (18u << 20));
  __bf16* Wvb = (__bf16*)(ws + (20u << 20));
  __bf16* Wob = (__bf16*)(ws + (22u << 20));
  __bf16* Qb  = (__bf16*)(ws + (24u << 20));         // 16 MB
  __bf16* Kb  = (__bf16*)(ws + (40u << 20));         // 16 MB
  __bf16* Vtb = (__bf16*)(ws + (56u << 20));         // 16 MB (ends at 72 MB)
  __bf16* Ub  = xb;

  cvt_bf16<<<8192, 256, 0, stream>>>(x, xb, 8192 * 1024 / 4);
  cvt_w4<<<dim3(1024, 4), 256, 0, stream>>>(Wq, Wk, Wv, Wo, Wqb, Wkb, Wvb, Wob);

  dim3 gg(8, 32);  // (bn, bm): 256 blocks = 1/CU
  const size_t lds = 131072;
  gemm256<0><<<gg, 512, lds, stream>>>(xb, Wqb, Qb,  fcos, fsin);
  gemm256<1><<<gg, 512, lds, stream>>>(xb, Wkb, Kb,  fcos, fsin);
  gemm256<2><<<gg, 512, lds, stream>>>(xb, Wvb, Vtb, nullptr, nullptr);
  attn_fwd<<<dim3(8, 64), 512, 0, stream>>>(Qb, Kb, Vtb, Ub);
  gemm256<3><<<gg, 512, lds, stream>>>(Ub, Wob, d_out, nullptr, nullptr);
}

// Round 9
// 187.299 us; speedup vs baseline: 1.8663x; 1.1239x over previous
//
#include <hip/hip_runtime.h>
#include <hip/hip_bf16.h>

typedef __attribute__((ext_vector_type(8))) __bf16 bf16x8;
typedef __attribute__((ext_vector_type(4))) __bf16 bf16x4;
typedef __attribute__((ext_vector_type(4))) float f32x4;
typedef __attribute__((ext_vector_type(2))) unsigned int u32x2;

static __device__ __forceinline__ f32x4 mfma_bf16(bf16x8 a, bf16x8 b, f32x4 c) {
  return __builtin_amdgcn_mfma_f32_16x16x32_bf16(a, b, c, 0, 0, 0);
}

// async global->LDS, 16B per lane. LDS dest must be linear in lane order.
static __device__ __forceinline__ void gload_lds16(const void* g, void* l) {
  __builtin_amdgcn_global_load_lds(
      (__attribute__((address_space(1))) unsigned int*)g,
      (__attribute__((address_space(3))) unsigned int*)l, 16, 0, 0);
}

// packed f32x2 -> bf16x2 in one VALU op (T12 recipe; no builtin on gfx950)
static __device__ __forceinline__ unsigned int cvt_pk_bf16(float lo, float hi) {
  unsigned int r;
  asm volatile("v_cvt_pk_bf16_f32 %0, %1, %2" : "=v"(r) : "v"(lo), "v"(hi));
  return r;
}

// ---------------------------------------------------------------- fp32 -> bf16
__global__ void cvt_bf16(const float* __restrict__ in, __bf16* __restrict__ out, int n4) {
  int i = blockIdx.x * blockDim.x + threadIdx.x;
  if (i >= n4) return;
  f32x4 v = ((const f32x4*)in)[i];
  bf16x4 o;
#pragma unroll
  for (int k = 0; k < 4; ++k) o[k] = (__bf16)v[k];
  ((bf16x4*)out)[i] = o;
}

// 4 weight matrices in one launch (1024x1024 each)
__global__ void cvt_w4(const float* __restrict__ w0, const float* __restrict__ w1,
                       const float* __restrict__ w2, const float* __restrict__ w3,
                       __bf16* __restrict__ o0, __bf16* __restrict__ o1,
                       __bf16* __restrict__ o2, __bf16* __restrict__ o3) {
  const float* in; __bf16* out;
  switch (blockIdx.y) {
    case 0: in = w0; out = o0; break;
    case 1: in = w1; out = o1; break;
    case 2: in = w2; out = o2; break;
    default: in = w3; out = o3; break;
  }
  int i = blockIdx.x * blockDim.x + threadIdx.x;
  f32x4 v = ((const f32x4*)in)[i];
  bf16x4 o;
#pragma unroll
  for (int k = 0; k < 4; ++k) o[k] = (__bf16)v[k];
  ((bf16x4*)out)[i] = o;
}

// ---------------------------------------------------------------- GEMM  C = A @ W^T
// 256x128 tile, BK=64, 8 waves as 4M x 2N (64x64 per wave). 2 phases/K-tile,
// counted vmcnt(4) with the publication barrier in the prior phase (R8-verified).
// XCD swizzle: same-bm blocks (sharing the A panel) land on one XCD's L2.
template <int MODE>
__global__ __launch_bounds__(512, 1)
void gemm256(const __bf16* __restrict__ A, const __bf16* __restrict__ W,
             void* __restrict__ outp,
             const float* __restrict__ fcos, const float* __restrict__ fsin) {
  constexpr int K = 1024;
  constexpr int NT = K / 64;  // 16 K-tiles
  extern __shared__ __align__(16) __bf16 dynlds[];
  __bf16* Al = dynlds;            // 3 slots x 16384 elems (256x64)
  __bf16* Bl = dynlds + 49152;    // 2 slots x  8192 elems (128x64)

  const int t = threadIdx.x;
  const int lane = t & 63, wave = t >> 6;
  const int g = lane >> 4, ln = lane & 15;
  const int wm = wave >> 1, wn = wave & 1;  // 4M x 2N -> per-wave 64x64
  // XCD-aware remap (bijective over 256 blocks): same-bm -> same lin%8 (XCD)
  const int lin = blockIdx.x + blockIdx.y * 8;
  const int bm = (lin & 7) + 8 * ((lin >> 3) & 3);
  const int bn = lin >> 5;

  f32x4 acc[4][4] = {};

  // ---- staging addressing (pre-swizzled source) ----
  const int srow8 = t >> 3;                                   // 0..63 (+c*64)
  const int scole = (((t & 7) ^ ((t >> 3) & 7)) << 3);        // swizzled elem col
  const __bf16* Ag = A + (size_t)(bm * 256 + srow8) * K + scole;
  const __bf16* Wg = W + (size_t)(bn * 128 + srow8) * K + scole;

#define ISSUE_A(kt, slot)                                                   \
  {                                                                         \
    const int k0 = (kt) * 64;                                               \
    __bf16* d = Al + (slot) * 16384 + t * 8;                                \
    gload_lds16(Ag + k0, d);                                                \
    gload_lds16(Ag + (size_t)64 * K + k0, d + 4096);                        \
    gload_lds16(Ag + (size_t)128 * K + k0, d + 8192);                       \
    gload_lds16(Ag + (size_t)192 * K + k0, d + 12288);                      \
  }
#define ISSUE_B(kt, slot)                                                   \
  {                                                                         \
    const int k0 = (kt) * 64;                                               \
    __bf16* d = Bl + (slot) * 8192 + t * 8;                                 \
    gload_lds16(Wg + k0, d);                                                \
    gload_lds16(Wg + (size_t)64 * K + k0, d + 4096);                        \
  }

  // ---- fragment read addressing (swizzled) ----
  const int axr = ln & 7;
  int aoff[4], boff[4];
#pragma unroll
  for (int i = 0; i < 4; ++i) aoff[i] = (wm * 64 + i * 16 + ln) * 64;
#pragma unroll
  for (int j = 0; j < 4; ++j) boff[j] = (wn * 64 + j * 16 + ln) * 64;

  // prologue: B(0), A(0), A(1); publish tile 0
  ISSUE_B(0, 0);
  ISSUE_A(0, 0);
  ISSUE_A(1, 1);
  asm volatile("s_waitcnt vmcnt(4)" ::: "memory");  // B0+A0 done, A1 in flight
  __builtin_amdgcn_s_barrier();

  int sa = 0;  // A slot of current tile (tt % 3)
  for (int tt = 0; tt < NT; ++tt) {
    const __bf16* Ab = Al + sa * 16384;
    const __bf16* Bb = Bl + (tt & 1) * 8192;
    bf16x8 af[4], bf[4];

    // ---------------- phase 0 : k-slice 0 (tile tt published) ----------------
#pragma unroll
    for (int i = 0; i < 4; ++i)
      af[i] = *(const bf16x8*)(Ab + aoff[i] + ((g ^ axr) << 3));
#pragma unroll
    for (int j = 0; j < 4; ++j)
      bf[j] = *(const bf16x8*)(Bb + boff[j] + ((g ^ axr) << 3));
    if (tt + 1 < NT) ISSUE_B(tt + 1, (tt + 1) & 1);
    if (tt + 2 < NT) ISSUE_A(tt + 2, sa == 0 ? 2 : sa - 1);  // (tt+2)%3
    __builtin_amdgcn_s_barrier();
    asm volatile("s_waitcnt lgkmcnt(0)" ::: "memory");
    __builtin_amdgcn_sched_barrier(0);
    __builtin_amdgcn_s_setprio(1);
#pragma unroll
    for (int i = 0; i < 4; ++i)
#pragma unroll
      for (int j = 0; j < 4; ++j)
        acc[i][j] = mfma_bf16(af[i], bf[j], acc[i][j]);
    __builtin_amdgcn_s_setprio(0);
    __builtin_amdgcn_s_barrier();

    // ---------------- phase 1 : k-slice 1 + publish tile tt+1 ----------------
#pragma unroll
    for (int i = 0; i < 4; ++i)
      af[i] = *(const bf16x8*)(Ab + aoff[i] + (((4 | g) ^ axr) << 3));
#pragma unroll
    for (int j = 0; j < 4; ++j)
      bf[j] = *(const bf16x8*)(Bb + boff[j] + (((4 | g) ^ axr) << 3));
    if (tt < NT - 2) { asm volatile("s_waitcnt vmcnt(4)" ::: "memory"); }
    else             { asm volatile("s_waitcnt vmcnt(0)" ::: "memory"); }
    __builtin_amdgcn_s_barrier();
    asm volatile("s_waitcnt lgkmcnt(0)" ::: "memory");
    __builtin_amdgcn_sched_barrier(0);
    __builtin_amdgcn_s_setprio(1);
#pragma unroll
    for (int i = 0; i < 4; ++i)
#pragma unroll
      for (int j = 0; j < 4; ++j)
        acc[i][j] = mfma_bf16(af[i], bf[j], acc[i][j]);
    __builtin_amdgcn_s_setprio(0);
    __builtin_amdgcn_s_barrier();

    sa = (sa == 2) ? 0 : sa + 1;
  }
#undef ISSUE_A
#undef ISSUE_B

  // ---- epilogue. D-layout: col=ln, row=g*4+r within each 16x16 frag ----
#pragma unroll
  for (int i = 0; i < 4; ++i) {
    const int mbase = bm * 256 + wm * 64 + i * 16 + g * 4;
#pragma unroll
    for (int j = 0; j < 4; ++j) {
      const int col = bn * 128 + wn * 64 + j * 16 + ln;
      if constexpr (MODE == 0 || MODE == 1) {
        const int fi = (col & 63) >> 1;
        const bool odd = (col & 1) != 0;
        __bf16* O = (__bf16*)outp;
#pragma unroll
        for (int r = 0; r < 4; ++r) {
          const int row = mbase + r;
          const int tok = row & 2047;
          const float cs = fcos[tok * 32 + fi];
          const float sn = fsin[tok * 32 + fi];
          const float own = acc[i][j][r];
          const float oth = __shfl_xor(own, 1);  // partner column d^1
          float val = own * cs + (odd ? oth * sn : -oth * sn);
          if constexpr (MODE == 0) val *= 0.1803368802f;  // 0.125 * log2(e)
          O[(size_t)row * 1024 + col] = (__bf16)val;
        }
      } else if constexpr (MODE == 2) {
        __bf16* O = (__bf16*)outp;
        const int bb = mbase >> 11;
        const int tok = mbase & 2047;
        bf16x4 pk;
#pragma unroll
        for (int r = 0; r < 4; ++r) pk[r] = (__bf16)acc[i][j][r];
        *(bf16x4*)(O + ((size_t)(bb * 1024 + col)) * 2048 + tok) = pk;
      } else {
        float* O = (float*)outp;
#pragma unroll
        for (int r = 0; r < 4; ++r)
          O[(size_t)(mbase + r) * 1024 + col] = acc[i][j][r];
      }
    }
  }
}

// ---------------------------------------------------------------- flash attention
// Swapped-operand, paired strips, 512 threads (R5 structure).
// NEW: XCD-aware block remap so all 8 blocks sharing one (b,h)'s K/V land on
// the same XCD (per-XCD KV working set = 8 bh x 512 KB = 4 MB = L2 size);
// cvt_pk P-packing; max3-shaped max tree.
__global__ __launch_bounds__(512, 4)
void attn_fwd(const __bf16* __restrict__ Q, const __bf16* __restrict__ Kk,
              const __bf16* __restrict__ Vt, __bf16* __restrict__ U) {
  constexpr int S = 2048;
  __shared__ __align__(16) __bf16 Klds[2][2 * 64 * 32];
  __shared__ __align__(16) __bf16 Vlds[2][2 * 64 * 32];
  __shared__ __align__(16) unsigned int Plds[8][16 * 36];

  const int t = threadIdx.x;
  const int lane = t & 63, wave = t >> 6;
  const int g = lane >> 4, ln = lane & 15;
  // XCD-aware bijective remap of (qt, bh) over 512 blocks:
  // xcd = lin%8 = bh>>3, so all 8 qt-blocks of one bh share an XCD L2.
  const int lin = blockIdx.x + blockIdx.y * 8;
  const int bh = (lin & 7) * 8 + ((lin >> 3) & 7);
  const int qt = lin >> 6;
  const int b = bh >> 4, h = bh & 15;
  const int q0s[2] = {qt * 128, (15 - qt) * 128};
  const int nts[2] = {2 * qt + 2, 32 - 2 * qt};

  bf16x8 qf[2][2];
#pragma unroll
  for (int s2 = 0; s2 < 2; ++s2) {
    const __bf16* Qb = Q + ((size_t)(b * S + q0s[s2] + wave * 16 + ln)) * 1024 + h * 64;
    qf[s2][0] = *(const bf16x8*)(Qb + g * 8);
    qf[s2][1] = *(const bf16x8*)(Qb + 32 + g * 8);
  }

  f32x4 o[2][4] = {};
  float mrow[2], lrow[2];
#pragma unroll
  for (int s2 = 0; s2 < 2; ++s2) { mrow[s2] = -3.0e38f; lrow[s2] = 0.f; }

  const int half = t >> 8;
  const int srow = (t >> 2) & 63;
  const int scol = (t & 3) * 8;
  const __bf16* Kg = Kk + ((size_t)(b * S + srow)) * 1024 + h * 64 + half * 32 + scol;
  const __bf16* Vg = Vt + ((size_t)(b * 1024 + h * 64 + srow)) * 2048 + half * 32 + scol;
  const int nt = nts[1];

  gload_lds16(Kg, (__bf16*)Klds[0] + t * 8);
  gload_lds16(Vg, (__bf16*)Vlds[0] + t * 8);
  __syncthreads();

  for (int kt = 0; kt < nt; ++kt) {
    const int cur = kt & 1;
    if (kt + 1 < nt) {
      const size_t kv1 = (size_t)(kt + 1) * 64;
      gload_lds16(Kg + kv1 * 1024, (__bf16*)Klds[cur ^ 1] + t * 8);
      gload_lds16(Vg + kv1, (__bf16*)Vlds[cur ^ 1] + t * 8);
    }
    const int kv0 = kt * 64;

#pragma unroll
    for (int s2 = 0; s2 < 2; ++s2) {
      if (kt >= nts[s2]) continue;

      f32x4 sa[4] = {};
      __builtin_amdgcn_s_setprio(1);
#pragma unroll
      for (int s = 0; s < 2; ++s) {
#pragma unroll
        for (int c = 0; c < 4; ++c) {
          bf16x8 kf = *(const bf16x8*)(Klds[cur] + s * 2048 + (c * 16 + ln) * 32 + g * 8);
          sa[c] = mfma_bf16(kf, qf[s2][s], sa[c]);
        }
      }
      __builtin_amdgcn_s_setprio(0);

      const int rfbase = q0s[s2] + wave * 16;
      const int rq = rfbase + ln;
      if (kv0 + 63 > rfbase) {
#pragma unroll
        for (int c = 0; c < 4; ++c)
#pragma unroll
          for (int r = 0; r < 4; ++r)
            if (kv0 + c * 16 + g * 4 + r > rq) sa[c][r] = -1e30f;
      }

      // in-lane max of 16 values, max3-shaped (8 ops if fused)
      const float a0 = fmaxf(fmaxf(sa[0][0], sa[0][1]), sa[0][2]);
      const float a1 = fmaxf(fmaxf(sa[0][3], sa[1][0]), sa[1][1]);
      const float a2 = fmaxf(fmaxf(sa[1][2], sa[1][3]), sa[2][0]);
      const float a3 = fmaxf(fmaxf(sa[2][1], sa[2][2]), sa[2][3]);
      const float a4 = fmaxf(fmaxf(sa[3][0], sa[3][1]), sa[3][2]);
      const float b0 = fmaxf(fmaxf(a0, a1), a2);
      const float b1 = fmaxf(fmaxf(a3, a4), sa[3][3]);
      float pm = fmaxf(b0, b1);

      if (__any(pm > mrow[s2] + 8.f)) {
        pm = fmaxf(pm, __shfl_xor(pm, 16));
        pm = fmaxf(pm, __shfl_xor(pm, 32));
        const float mn = fmaxf(mrow[s2], pm);
        const float alpha = exp2f(mrow[s2] - mn);
        mrow[s2] = mn;
        lrow[s2] *= alpha;
#pragma unroll
        for (int c2 = 0; c2 < 4; ++c2)
#pragma unroll
          for (int r = 0; r < 4; ++r) o[s2][c2][r] *= alpha;
      }

      float p[4][4];
#pragma unroll
      for (int c = 0; c < 4; ++c)
#pragma unroll
        for (int r = 0; r < 4; ++r) p[c][r] = exp2f(sa[c][r] - mrow[s2]);

      float ts[8];
#pragma unroll
      for (int i = 0; i < 8; ++i) ts[i] = p[i >> 2][i & 3] + p[2 + (i >> 2)][i & 3];
#pragma unroll
      for (int st = 4; st >= 1; st >>= 1)
#pragma unroll
        for (int i = 0; i < st; ++i) ts[i] += ts[i + st];
      float rs = ts[0];
      rs += __shfl_xor(rs, 16);
      rs += __shfl_xor(rs, 32);
      lrow[s2] += rs;

      unsigned int* Pw = Plds[wave] + ln * 36;
#pragma unroll
      for (int c = 0; c < 4; ++c) {
        u32x2 w;
        w[0] = cvt_pk_bf16(p[c][0], p[c][1]);
        w[1] = cvt_pk_bf16(p[c][2], p[c][3]);
        *(u32x2*)(Pw + 8 * c + 2 * g) = w;
      }

      __builtin_amdgcn_s_setprio(1);
#pragma unroll
      for (int sh = 0; sh < 2; ++sh) {
        bf16x8 pb = *(const bf16x8*)((const __bf16*)(Plds[wave]) + ln * 72 + sh * 32 + g * 8);
#pragma unroll
        for (int c2 = 0; c2 < 4; ++c2) {
          bf16x8 vf = *(const bf16x8*)(Vlds[cur] + sh * 2048 + (c2 * 16 + ln) * 32 + g * 8);
          o[s2][c2] = mfma_bf16(vf, pb, o[s2][c2]);
        }
      }
      __builtin_amdgcn_s_setprio(0);
    }
    __syncthreads();
  }

#pragma unroll
  for (int s2 = 0; s2 < 2; ++s2) {
    const float rl = 1.0f / lrow[s2];
    __bf16* Ub = U + ((size_t)(b * S + q0s[s2] + wave * 16 + ln)) * 1024 + h * 64;
#pragma unroll
    for (int c2 = 0; c2 < 4; ++c2) {
      bf16x4 pk4;
#pragma unroll
      for (int r = 0; r < 4; ++r) pk4[r] = (__bf16)(o[s2][c2][r] * rl);
      *(bf16x4*)(Ub + 16 * c2 + 4 * g) = pk4;
    }
  }
}

// ---------------------------------------------------------------- launch
extern "C" void kernel_launch(void* const* d_in, const int* in_sizes, int n_in,
                              void* d_out, int out_size, void* d_ws, size_t ws_size,
                              hipStream_t stream) {
  const float* x    = (const float*)d_in[0];
  const float* fcos = (const float*)d_in[1];
  const float* fsin = (const float*)d_in[2];
  const float* Wq   = (const float*)d_in[3];
  const float* Wk   = (const float*)d_in[4];
  const float* Wv   = (const float*)d_in[5];
  const float* Wo   = (const float*)d_in[6];

  char* ws = (char*)d_ws;
  __bf16* xb  = (__bf16*)(ws);                       // 16 MB
  __bf16* Wqb = (__bf16*)(ws + (16u << 20));         // 2 MB each
  __bf16* Wkb = (__bf16*)(ws + (18u << 20));
  __bf16* Wvb = (__bf16*)(ws + (20u << 20));
  __bf16* Wob = (__bf16*)(ws + (22u << 20));
  __bf16* Qb  = (__bf16*)(ws + (24u << 20));         // 16 MB
  __bf16* Kb  = (__bf16*)(ws + (40u << 20));         // 16 MB
  __bf16* Vtb = (__bf16*)(ws + (56u << 20));         // 16 MB (ends at 72 MB)
  __bf16* Ub  = xb;

  cvt_bf16<<<8192, 256, 0, stream>>>(x, xb, 8192 * 1024 / 4);
  cvt_w4<<<dim3(1024, 4), 256, 0, stream>>>(Wq, Wk, Wv, Wo, Wqb, Wkb, Wvb, Wob);

  dim3 gg(8, 32);  // 256 blocks = 1/CU
  const size_t lds = 131072;
  gemm256<0><<<gg, 512, lds, stream>>>(xb, Wqb, Qb,  fcos, fsin);
  gemm256<1><<<gg, 512, lds, stream>>>(xb, Wkb, Kb,  fcos, fsin);
  gemm256<2><<<gg, 512, lds, stream>>>(xb, Wvb, Vtb, nullptr, nullptr);
  attn_fwd<<<dim3(8, 64), 512, 0, stream>>>(Qb, Kb, Vtb, Ub);
  gemm256<3><<<gg, 512, lds, stream>>>(Ub, Wob, d_out, nullptr, nullptr);
}

// Round 11
// 187.218 us; speedup vs baseline: 1.8671x; 1.0004x over previous
//
#include <hip/hip_runtime.h>
#include <hip/hip_bf16.h>

typedef __attribute__((ext_vector_type(8))) __bf16 bf16x8;
typedef __attribute__((ext_vector_type(4))) __bf16 bf16x4;
typedef __attribute__((ext_vector_type(4))) float f32x4;
typedef __attribute__((ext_vector_type(2))) unsigned int u32x2;

static __device__ __forceinline__ f32x4 mfma_bf16(bf16x8 a, bf16x8 b, f32x4 c) {
  return __builtin_amdgcn_mfma_f32_16x16x32_bf16(a, b, c, 0, 0, 0);
}

// async global->LDS, 16B per lane. LDS dest must be linear in lane order.
static __device__ __forceinline__ void gload_lds16(const void* g, void* l) {
  __builtin_amdgcn_global_load_lds(
      (__attribute__((address_space(1))) unsigned int*)g,
      (__attribute__((address_space(3))) unsigned int*)l, 16, 0, 0);
}

// packed f32x2 -> bf16x2 in one VALU op
static __device__ __forceinline__ unsigned int cvt_pk_bf16(float lo, float hi) {
  unsigned int r;
  asm volatile("v_cvt_pk_bf16_f32 %0, %1, %2" : "=v"(r) : "v"(lo), "v"(hi));
  return r;
}

// ---------------------------------------------------------------- fp32 -> bf16
__global__ void cvt_bf16(const float* __restrict__ in, __bf16* __restrict__ out, int n4) {
  int i = blockIdx.x * blockDim.x + threadIdx.x;
  if (i >= n4) return;
  f32x4 v = ((const f32x4*)in)[i];
  bf16x4 o;
#pragma unroll
  for (int k = 0; k < 4; ++k) o[k] = (__bf16)v[k];
  ((bf16x4*)out)[i] = o;
}

// 4 weight matrices in one launch (1024x1024 each)
__global__ void cvt_w4(const float* __restrict__ w0, const float* __restrict__ w1,
                       const float* __restrict__ w2, const float* __restrict__ w3,
                       __bf16* __restrict__ o0, __bf16* __restrict__ o1,
                       __bf16* __restrict__ o2, __bf16* __restrict__ o3) {
  const float* in; __bf16* out;
  switch (blockIdx.y) {
    case 0: in = w0; out = o0; break;
    case 1: in = w1; out = o1; break;
    case 2: in = w2; out = o2; break;
    default: in = w3; out = o3; break;
  }
  int i = blockIdx.x * blockDim.x + threadIdx.x;
  f32x4 v = ((const f32x4*)in)[i];
  bf16x4 o;
#pragma unroll
  for (int k = 0; k < 4; ++k) o[k] = (__bf16)v[k];
  ((bf16x4*)out)[i] = o;
}

// ================================================================ GEMM core
// 256x128 tile, BK=64, 8 waves as 4M x 2N. 2 phases/K-tile, counted vmcnt(4)
// with the publication barrier in the prior phase (R8-verified invariant).
// Statement macro: declares t/lane/wave/g/ln/wm/wn/acc and runs the K loop.
// Requires `A`, `W`, `bm`, `bn` in scope. Epilogue is open-coded after.
#define ISSUE_A(kt, slot)                                                   \
  {                                                                         \
    const int k0 = (kt) * 64;                                               \
    __bf16* d = Al + (slot) * 16384 + t * 8;                                \
    gload_lds16(Ag + k0, d);                                                \
    gload_lds16(Ag + (size_t)64 * K + k0, d + 4096);                        \
    gload_lds16(Ag + (size_t)128 * K + k0, d + 8192);                       \
    gload_lds16(Ag + (size_t)192 * K + k0, d + 12288);                      \
  }
#define ISSUE_B(kt, slot)                                                   \
  {                                                                         \
    const int k0 = (kt) * 64;                                               \
    __bf16* d = Bl + (slot) * 8192 + t * 8;                                 \
    gload_lds16(Wg + k0, d);                                                \
    gload_lds16(Wg + (size_t)64 * K + k0, d + 4096);                        \
  }

#define GEMM_PIPELINE                                                       \
  constexpr int K = 1024;                                                   \
  constexpr int NT = K / 64;                                                \
  extern __shared__ __align__(16) __bf16 dynlds[];                          \
  __bf16* Al = dynlds;                                                      \
  __bf16* Bl = dynlds + 49152;                                              \
  const int t = threadIdx.x;                                                \
  const int lane = t & 63, wave = t >> 6;                                   \
  const int g = lane >> 4, ln = lane & 15;                                  \
  const int wm = wave >> 1, wn = wave & 1;                                  \
  f32x4 acc[4][4] = {};                                                     \
  const int srow8 = t >> 3;                                                 \
  const int scole = (((t & 7) ^ ((t >> 3) & 7)) << 3);                      \
  const __bf16* Ag = A + (size_t)(bm * 256 + srow8) * K + scole;            \
  const __bf16* Wg = W + (size_t)(bn * 128 + srow8) * K + scole;            \
  const int axr = ln & 7;                                                   \
  int aoff[4], boff[4];                                                     \
  _Pragma("unroll") for (int i = 0; i < 4; ++i)                             \
    aoff[i] = (wm * 64 + i * 16 + ln) * 64;                                 \
  _Pragma("unroll") for (int j = 0; j < 4; ++j)                             \
    boff[j] = (wn * 64 + j * 16 + ln) * 64;                                 \
  ISSUE_B(0, 0); ISSUE_A(0, 0); ISSUE_A(1, 1);                              \
  asm volatile("s_waitcnt vmcnt(4)" ::: "memory");                          \
  __builtin_amdgcn_s_barrier();                                             \
  int sa = 0;                                                               \
  for (int tt = 0; tt < NT; ++tt) {                                         \
    const __bf16* Ab = Al + sa * 16384;                                     \
    const __bf16* Bb = Bl + (tt & 1) * 8192;                                \
    bf16x8 af[4], bf[4];                                                    \
    _Pragma("unroll") for (int i = 0; i < 4; ++i)                           \
      af[i] = *(const bf16x8*)(Ab + aoff[i] + ((g ^ axr) << 3));            \
    _Pragma("unroll") for (int j = 0; j < 4; ++j)                           \
      bf[j] = *(const bf16x8*)(Bb + boff[j] + ((g ^ axr) << 3));            \
    if (tt + 1 < NT) ISSUE_B(tt + 1, (tt + 1) & 1);                         \
    if (tt + 2 < NT) ISSUE_A(tt + 2, sa == 0 ? 2 : sa - 1);                 \
    __builtin_amdgcn_s_barrier();                                           \
    asm volatile("s_waitcnt lgkmcnt(0)" ::: "memory");                      \
    __builtin_amdgcn_sched_barrier(0);                                      \
    __builtin_amdgcn_s_setprio(1);                                          \
    _Pragma("unroll") for (int i = 0; i < 4; ++i)                           \
      _Pragma("unroll") for (int j = 0; j < 4; ++j)                         \
        acc[i][j] = mfma_bf16(af[i], bf[j], acc[i][j]);                     \
    __builtin_amdgcn_s_setprio(0);                                          \
    __builtin_amdgcn_s_barrier();                                           \
    _Pragma("unroll") for (int i = 0; i < 4; ++i)                           \
      af[i] = *(const bf16x8*)(Ab + aoff[i] + (((4 | g) ^ axr) << 3));      \
    _Pragma("unroll") for (int j = 0; j < 4; ++j)                           \
      bf[j] = *(const bf16x8*)(Bb + boff[j] + (((4 | g) ^ axr) << 3));      \
    if (tt < NT - 2) { asm volatile("s_waitcnt vmcnt(4)" ::: "memory"); }   \
    else             { asm volatile("s_waitcnt vmcnt(0)" ::: "memory"); }   \
    __builtin_amdgcn_s_barrier();                                           \
    asm volatile("s_waitcnt lgkmcnt(0)" ::: "memory");                      \
    __builtin_amdgcn_sched_barrier(0);                                      \
    __builtin_amdgcn_s_setprio(1);                                          \
    _Pragma("unroll") for (int i = 0; i < 4; ++i)                           \
      _Pragma("unroll") for (int j = 0; j < 4; ++j)                         \
        acc[i][j] = mfma_bf16(af[i], bf[j], acc[i][j]);                     \
    __builtin_amdgcn_s_setprio(0);                                          \
    __builtin_amdgcn_s_barrier();                                           \
    sa = (sa == 2) ? 0 : sa + 1;                                            \
  }

// ---------------------------------------------------------------- fused QKV
// 768 blocks: bn3 = 0..23 (mode = bn3>>3: 0=Q,1=K,2=V), bm = 0..31.
// XCD remap groups same-bm (shared x panel) blocks on one XCD.
__global__ __launch_bounds__(512, 1)
void gemm_qkv(const __bf16* __restrict__ A,
              const __bf16* __restrict__ Wqp, const __bf16* __restrict__ Wkp,
              const __bf16* __restrict__ Wvp,
              __bf16* __restrict__ Qo, __bf16* __restrict__ Ko,
              __bf16* __restrict__ Vo,
              const float* __restrict__ fcos, const float* __restrict__ fsin) {
  const int lin = blockIdx.x + blockIdx.y * 24;
  const int bm = (lin & 7) + 8 * ((lin >> 3) / 24);
  const int bn3 = (lin >> 3) % 24;
  const int mode = bn3 >> 3, bn = bn3 & 7;
  const __bf16* W = (mode == 0) ? Wqp : (mode == 1) ? Wkp : Wvp;

  GEMM_PIPELINE

#pragma unroll
  for (int i = 0; i < 4; ++i) {
    const int mbase = bm * 256 + wm * 64 + i * 16 + g * 4;
#pragma unroll
    for (int j = 0; j < 4; ++j) {
      const int col = bn * 128 + wn * 64 + j * 16 + ln;
      if (mode < 2) {
        const int fi = (col & 63) >> 1;
        const bool odd = (col & 1) != 0;
        __bf16* O = (mode == 0) ? Qo : Ko;
        const float sc = (mode == 0) ? 0.1803368802f : 1.0f;
#pragma unroll
        for (int r = 0; r < 4; ++r) {
          const int row = mbase + r;
          const int tok = row & 2047;
          const float cs = fcos[tok * 32 + fi];
          const float sn = fsin[tok * 32 + fi];
          const float own = acc[i][j][r];
          const float oth = __shfl_xor(own, 1);
          O[(size_t)row * 1024 + col] =
              (__bf16)((own * cs + (odd ? oth * sn : -oth * sn)) * sc);
        }
      } else {
        const int bb = mbase >> 11;
        const int tok = mbase & 2047;
        bf16x4 pk;
#pragma unroll
        for (int r = 0; r < 4; ++r) pk[r] = (__bf16)acc[i][j][r];
        *(bf16x4*)(Vo + ((size_t)(bb * 1024 + col)) * 2048 + tok) = pk;
      }
    }
  }
}

// ---------------------------------------------------------------- out GEMM (fp32)
__global__ __launch_bounds__(512, 1)
void gemm_out(const __bf16* __restrict__ A, const __bf16* __restrict__ W,
              float* __restrict__ outp) {
  const int lin = blockIdx.x + blockIdx.y * 8;
  const int bm = (lin & 7) + 8 * ((lin >> 3) & 3);
  const int bn = lin >> 5;

  GEMM_PIPELINE

#pragma unroll
  for (int i = 0; i < 4; ++i) {
    const int mbase = bm * 256 + wm * 64 + i * 16 + g * 4;
#pragma unroll
    for (int j = 0; j < 4; ++j) {
      const int col = bn * 128 + wn * 64 + j * 16 + ln;
#pragma unroll
      for (int r = 0; r < 4; ++r)
        outp[(size_t)(mbase + r) * 1024 + col] = acc[i][j][r];
    }
  }
}

// ---------------------------------------------------------------- flash attention
// Swapped-operand, paired strips, XCD-remapped (R9). NEW: in the shared-prefix
// phase, one fused QK loop reuses each K ds_read for BOTH strips (halves K
// reads/MFMA), and SM1's VALU can overlap PV0's MFMAs. P double-buffered per
// strip so PV0 reads aren't clobbered by pack1.
static __device__ __forceinline__ void sm_pack_pv(
    f32x4* sa, float& m, float& l, f32x4* o,
    unsigned int* Pw, const __bf16* Vb, const int g, const int ln) {
  const float a0 = fmaxf(fmaxf(sa[0][0], sa[0][1]), sa[0][2]);
  const float a1 = fmaxf(fmaxf(sa[0][3], sa[1][0]), sa[1][1]);
  const float a2 = fmaxf(fmaxf(sa[1][2], sa[1][3]), sa[2][0]);
  const float a3 = fmaxf(fmaxf(sa[2][1], sa[2][2]), sa[2][3]);
  const float a4 = fmaxf(fmaxf(sa[3][0], sa[3][1]), sa[3][2]);
  float pm = fmaxf(fmaxf(fmaxf(a0, a1), a2), fmaxf(fmaxf(a3, a4), sa[3][3]));

  if (__any(pm > m + 8.f)) {
    pm = fmaxf(pm, __shfl_xor(pm, 16));
    pm = fmaxf(pm, __shfl_xor(pm, 32));
    const float mn = fmaxf(m, pm);
    const float alpha = exp2f(m - mn);
    m = mn;
    l *= alpha;
#pragma unroll
    for (int c2 = 0; c2 < 4; ++c2)
#pragma unroll
      for (int r = 0; r < 4; ++r) o[c2][r] *= alpha;
  }

  float p[4][4];
#pragma unroll
  for (int c = 0; c < 4; ++c)
#pragma unroll
    for (int r = 0; r < 4; ++r) p[c][r] = exp2f(sa[c][r] - m);

  float ts[8];
#pragma unroll
  for (int i = 0; i < 8; ++i) ts[i] = p[i >> 2][i & 3] + p[2 + (i >> 2)][i & 3];
#pragma unroll
  for (int st = 4; st >= 1; st >>= 1)
#pragma unroll
    for (int i = 0; i < st; ++i) ts[i] += ts[i + st];
  float rs = ts[0];
  rs += __shfl_xor(rs, 16);
  rs += __shfl_xor(rs, 32);
  l += rs;

  unsigned int* Pr = Pw + ln * 36;
#pragma unroll
  for (int c = 0; c < 4; ++c) {
    u32x2 w;
    w[0] = cvt_pk_bf16(p[c][0], p[c][1]);
    w[1] = cvt_pk_bf16(p[c][2], p[c][3]);
    *(u32x2*)(Pr + 8 * c + 2 * g) = w;
  }

  __builtin_amdgcn_s_setprio(1);
#pragma unroll
  for (int sh = 0; sh < 2; ++sh) {
    bf16x8 pb = *(const bf16x8*)((const __bf16*)Pw + ln * 72 + sh * 32 + g * 8);
#pragma unroll
    for (int c2 = 0; c2 < 4; ++c2) {
      bf16x8 vf = *(const bf16x8*)(Vb + sh * 2048 + (c2 * 16 + ln) * 32 + g * 8);
      o[c2] = mfma_bf16(vf, pb, o[c2]);
    }
  }
  __builtin_amdgcn_s_setprio(0);
}

__global__ __launch_bounds__(512, 4)
void attn_fwd(const __bf16* __restrict__ Q, const __bf16* __restrict__ Kk,
              const __bf16* __restrict__ Vt, __bf16* __restrict__ U) {
  constexpr int S = 2048;
  __shared__ __align__(16) __bf16 Klds[2][2 * 64 * 32];
  __shared__ __align__(16) __bf16 Vlds[2][2 * 64 * 32];
  __shared__ __align__(16) unsigned int Plds[2][8][16 * 36];  // [strip][wave]

  const int t = threadIdx.x;
  const int lane = t & 63, wave = t >> 6;
  const int g = lane >> 4, ln = lane & 15;
  const int lin = blockIdx.x + blockIdx.y * 8;
  const int bh = (lin & 7) * 8 + ((lin >> 3) & 7);
  const int qt = lin >> 6;
  const int b = bh >> 4, h = bh & 15;
  const int q0s[2] = {qt * 128, (15 - qt) * 128};
  const int nts[2] = {2 * qt + 2, 32 - 2 * qt};  // nts[0] < nts[1] always

  bf16x8 qf[2][2];
#pragma unroll
  for (int s2 = 0; s2 < 2; ++s2) {
    const __bf16* Qb = Q + ((size_t)(b * S + q0s[s2] + wave * 16 + ln)) * 1024 + h * 64;
    qf[s2][0] = *(const bf16x8*)(Qb + g * 8);
    qf[s2][1] = *(const bf16x8*)(Qb + 32 + g * 8);
  }

  f32x4 o[2][4] = {};
  float mrow[2], lrow[2];
#pragma unroll
  for (int s2 = 0; s2 < 2; ++s2) { mrow[s2] = -3.0e38f; lrow[s2] = 0.f; }

  const int half = t >> 8;
  const int srow = (t >> 2) & 63;
  const int scol = (t & 3) * 8;
  const __bf16* Kg = Kk + ((size_t)(b * S + srow)) * 1024 + h * 64 + half * 32 + scol;
  const __bf16* Vg = Vt + ((size_t)(b * 1024 + h * 64 + srow)) * 2048 + half * 32 + scol;
  const int nt = nts[1];

  gload_lds16(Kg, (__bf16*)Klds[0] + t * 8);
  gload_lds16(Vg, (__bf16*)Vlds[0] + t * 8);
  __syncthreads();

  for (int kt = 0; kt < nt; ++kt) {
    const int cur = kt & 1;
    if (kt + 1 < nt) {
      const size_t kv1 = (size_t)(kt + 1) * 64;
      gload_lds16(Kg + kv1 * 1024, (__bf16*)Klds[cur ^ 1] + t * 8);
      gload_lds16(Vg + kv1, (__bf16*)Vlds[cur ^ 1] + t * 8);
    }
    const int kv0 = kt * 64;

    if (kt < nts[0]) {
      // ---- both strips: fused QK (shared kf reads), then SM0;PV0;SM1;PV1 ----
      f32x4 sa0[4] = {}, sa1[4] = {};
      __builtin_amdgcn_s_setprio(1);
#pragma unroll
      for (int s = 0; s < 2; ++s) {
#pragma unroll
        for (int c = 0; c < 4; ++c) {
          bf16x8 kf = *(const bf16x8*)(Klds[cur] + s * 2048 + (c * 16 + ln) * 32 + g * 8);
          sa0[c] = mfma_bf16(kf, qf[0][s], sa0[c]);
          sa1[c] = mfma_bf16(kf, qf[1][s], sa1[c]);
        }
      }
      __builtin_amdgcn_s_setprio(0);

      const int rfbase0 = q0s[0] + wave * 16;
      const int rq0 = rfbase0 + ln;
      if (kv0 + 63 > rfbase0) {
#pragma unroll
        for (int c = 0; c < 4; ++c)
#pragma unroll
          for (int r = 0; r < 4; ++r)
            if (kv0 + c * 16 + g * 4 + r > rq0) sa0[c][r] = -1e30f;
      }
      // strip1 never masked in shared-prefix phase: (2qt+1)*64+63 < (15-qt)*128

      sm_pack_pv(sa0, mrow[0], lrow[0], o[0], Plds[0][wave], Vlds[cur], g, ln);
      sm_pack_pv(sa1, mrow[1], lrow[1], o[1], Plds[1][wave], Vlds[cur], g, ln);
    } else {
      // ---- single strip 1 ----
      f32x4 sa1[4] = {};
      __builtin_amdgcn_s_setprio(1);
#pragma unroll
      for (int s = 0; s < 2; ++s) {
#pragma unroll
        for (int c = 0; c < 4; ++c) {
          bf16x8 kf = *(const bf16x8*)(Klds[cur] + s * 2048 + (c * 16 + ln) * 32 + g * 8);
          sa1[c] = mfma_bf16(kf, qf[1][s], sa1[c]);
        }
      }
      __builtin_amdgcn_s_setprio(0);

      const int rfbase1 = q0s[1] + wave * 16;
      const int rq1 = rfbase1 + ln;
      if (kv0 + 63 > rfbase1) {
#pragma unroll
        for (int c = 0; c < 4; ++c)
#pragma unroll
          for (int r = 0; r < 4; ++r)
            if (kv0 + c * 16 + g * 4 + r > rq1) sa1[c][r] = -1e30f;
      }

      sm_pack_pv(sa1, mrow[1], lrow[1], o[1], Plds[1][wave], Vlds[cur], g, ln);
    }
    __syncthreads();
  }

#pragma unroll
  for (int s2 = 0; s2 < 2; ++s2) {
    const float rl = 1.0f / lrow[s2];
    __bf16* Ub = U + ((size_t)(b * S + q0s[s2] + wave * 16 + ln)) * 1024 + h * 64;
#pragma unroll
    for (int c2 = 0; c2 < 4; ++c2) {
      bf16x4 pk4;
#pragma unroll
      for (int r = 0; r < 4; ++r) pk4[r] = (__bf16)(o[s2][c2][r] * rl);
      *(bf16x4*)(Ub + 16 * c2 + 4 * g) = pk4;
    }
  }
}

// ---------------------------------------------------------------- launch
extern "C" void kernel_launch(void* const* d_in, const int* in_sizes, int n_in,
                              void* d_out, int out_size, void* d_ws, size_t ws_size,
                              hipStream_t stream) {
  const float* x    = (const float*)d_in[0];
  const float* fcos = (const float*)d_in[1];
  const float* fsin = (const float*)d_in[2];
  const float* Wq   = (const float*)d_in[3];
  const float* Wk   = (const float*)d_in[4];
  const float* Wv   = (const float*)d_in[5];
  const float* Wo   = (const float*)d_in[6];

  char* ws = (char*)d_ws;
  __bf16* xb  = (__bf16*)(ws);                       // 16 MB
  __bf16* Wqb = (__bf16*)(ws + (16u << 20));         // 2 MB each
  __bf16* Wkb = (__bf16*)(ws + (18u << 20));
  __bf16* Wvb = (__bf16*)(ws + (20u << 20));
  __bf16* Wob = (__bf16*)(ws + (22u << 20));
  __bf16* Qb  = (__bf16*)(ws + (24u << 20));         // 16 MB
  __bf16* Kb  = (__bf16*)(ws + (40u << 20));         // 16 MB
  __bf16* Vtb = (__bf16*)(ws + (56u << 20));         // 16 MB (ends at 72 MB)
  __bf16* Ub  = xb;

  cvt_bf16<<<8192, 256, 0, stream>>>(x, xb, 8192 * 1024 / 4);
  cvt_w4<<<dim3(1024, 4), 256, 0, stream>>>(Wq, Wk, Wv, Wo, Wqb, Wkb, Wvb, Wob);

  const size_t lds = 131072;
  gemm_qkv<<<dim3(24, 32), 512, lds, stream>>>(xb, Wqb, Wkb, Wvb, Qb, Kb, Vtb,
                                               fcos, fsin);
  attn_fwd<<<dim3(8, 64), 512, 0, stream>>>(Qb, Kb, Vtb, Ub);
  gemm_out<<<dim3(8, 32), 512, lds, stream>>>(Ub, Wob, (float*)d_out);
}

// Round 12
// 184.317 us; speedup vs baseline: 1.8965x; 1.0157x over previous
//
#include <hip/hip_runtime.h>
#include <hip/hip_bf16.h>

typedef __attribute__((ext_vector_type(8))) __bf16 bf16x8;
typedef __attribute__((ext_vector_type(4))) __bf16 bf16x4;
typedef __attribute__((ext_vector_type(4))) float f32x4;
typedef __attribute__((ext_vector_type(2))) unsigned int u32x2;

static __device__ __forceinline__ f32x4 mfma_bf16(bf16x8 a, bf16x8 b, f32x4 c) {
  return __builtin_amdgcn_mfma_f32_16x16x32_bf16(a, b, c, 0, 0, 0);
}

// async global->LDS, 16B per lane. LDS dest must be linear in lane order.
static __device__ __forceinline__ void gload_lds16(const void* g, void* l) {
  __builtin_amdgcn_global_load_lds(
      (__attribute__((address_space(1))) unsigned int*)g,
      (__attribute__((address_space(3))) unsigned int*)l, 16, 0, 0);
}

// packed f32x2 -> bf16x2 in one VALU op
static __device__ __forceinline__ unsigned int cvt_pk_bf16(float lo, float hi) {
  unsigned int r;
  asm volatile("v_cvt_pk_bf16_f32 %0, %1, %2" : "=v"(r) : "v"(lo), "v"(hi));
  return r;
}

// ---------------------------------------------------------------- fp32 -> bf16
__global__ void cvt_bf16(const float* __restrict__ in, __bf16* __restrict__ out, int n4) {
  int i = blockIdx.x * blockDim.x + threadIdx.x;
  if (i >= n4) return;
  f32x4 v = ((const f32x4*)in)[i];
  bf16x4 o;
#pragma unroll
  for (int k = 0; k < 4; ++k) o[k] = (__bf16)v[k];
  ((bf16x4*)out)[i] = o;
}

// 4 weight matrices in one launch (1024x1024 each)
__global__ void cvt_w4(const float* __restrict__ w0, const float* __restrict__ w1,
                       const float* __restrict__ w2, const float* __restrict__ w3,
                       __bf16* __restrict__ o0, __bf16* __restrict__ o1,
                       __bf16* __restrict__ o2, __bf16* __restrict__ o3) {
  const float* in; __bf16* out;
  switch (blockIdx.y) {
    case 0: in = w0; out = o0; break;
    case 1: in = w1; out = o1; break;
    case 2: in = w2; out = o2; break;
    default: in = w3; out = o3; break;
  }
  int i = blockIdx.x * blockDim.x + threadIdx.x;
  f32x4 v = ((const f32x4*)in)[i];
  bf16x4 o;
#pragma unroll
  for (int k = 0; k < 4; ++k) o[k] = (__bf16)v[k];
  ((bf16x4*)out)[i] = o;
}

// ================================================================ GEMM core
// 256x128 tile, BK=64, 8 waves as 4M x 2N. 2 phases/K-tile, counted vmcnt(4)
// with the publication barrier in the prior phase (R8-verified invariant).
#define ISSUE_A(kt, slot)                                                   \
  {                                                                         \
    const int k0 = (kt) * 64;                                               \
    __bf16* d = Al + (slot) * 16384 + t * 8;                                \
    gload_lds16(Ag + k0, d);                                                \
    gload_lds16(Ag + (size_t)64 * K + k0, d + 4096);                        \
    gload_lds16(Ag + (size_t)128 * K + k0, d + 8192);                       \
    gload_lds16(Ag + (size_t)192 * K + k0, d + 12288);                      \
  }
#define ISSUE_B(kt, slot)                                                   \
  {                                                                         \
    const int k0 = (kt) * 64;                                               \
    __bf16* d = Bl + (slot) * 8192 + t * 8;                                 \
    gload_lds16(Wg + k0, d);                                                \
    gload_lds16(Wg + (size_t)64 * K + k0, d + 4096);                        \
  }

#define GEMM_PIPELINE                                                       \
  constexpr int K = 1024;                                                   \
  constexpr int NT = K / 64;                                                \
  extern __shared__ __align__(16) __bf16 dynlds[];                          \
  __bf16* Al = dynlds;                                                      \
  __bf16* Bl = dynlds + 49152;                                              \
  const int t = threadIdx.x;                                                \
  const int lane = t & 63, wave = t >> 6;                                   \
  const int g = lane >> 4, ln = lane & 15;                                  \
  const int wm = wave >> 1, wn = wave & 1;                                  \
  f32x4 acc[4][4] = {};                                                     \
  const int srow8 = t >> 3;                                                 \
  const int scole = (((t & 7) ^ ((t >> 3) & 7)) << 3);                      \
  const __bf16* Ag = A + (size_t)(bm * 256 + srow8) * K + scole;            \
  const __bf16* Wg = W + (size_t)(bn * 128 + srow8) * K + scole;            \
  const int axr = ln & 7;                                                   \
  int aoff[4], boff[4];                                                     \
  _Pragma("unroll") for (int i = 0; i < 4; ++i)                             \
    aoff[i] = (wm * 64 + i * 16 + ln) * 64;                                 \
  _Pragma("unroll") for (int j = 0; j < 4; ++j)                             \
    boff[j] = (wn * 64 + j * 16 + ln) * 64;                                 \
  ISSUE_B(0, 0); ISSUE_A(0, 0); ISSUE_A(1, 1);                              \
  asm volatile("s_waitcnt vmcnt(4)" ::: "memory");                          \
  __builtin_amdgcn_s_barrier();                                             \
  int sa = 0;                                                               \
  for (int tt = 0; tt < NT; ++tt) {                                         \
    const __bf16* Ab = Al + sa * 16384;                                     \
    const __bf16* Bb = Bl + (tt & 1) * 8192;                                \
    bf16x8 af[4], bf[4];                                                    \
    _Pragma("unroll") for (int i = 0; i < 4; ++i)                           \
      af[i] = *(const bf16x8*)(Ab + aoff[i] + ((g ^ axr) << 3));            \
    _Pragma("unroll") for (int j = 0; j < 4; ++j)                           \
      bf[j] = *(const bf16x8*)(Bb + boff[j] + ((g ^ axr) << 3));            \
    if (tt + 1 < NT) ISSUE_B(tt + 1, (tt + 1) & 1);                         \
    if (tt + 2 < NT) ISSUE_A(tt + 2, sa == 0 ? 2 : sa - 1);                 \
    __builtin_amdgcn_s_barrier();                                           \
    asm volatile("s_waitcnt lgkmcnt(0)" ::: "memory");                      \
    __builtin_amdgcn_sched_barrier(0);                                      \
    __builtin_amdgcn_s_setprio(1);                                          \
    _Pragma("unroll") for (int i = 0; i < 4; ++i)                           \
      _Pragma("unroll") for (int j = 0; j < 4; ++j)                         \
        acc[i][j] = mfma_bf16(af[i], bf[j], acc[i][j]);                     \
    __builtin_amdgcn_s_setprio(0);                                          \
    __builtin_amdgcn_s_barrier();                                           \
    _Pragma("unroll") for (int i = 0; i < 4; ++i)                           \
      af[i] = *(const bf16x8*)(Ab + aoff[i] + (((4 | g) ^ axr) << 3));      \
    _Pragma("unroll") for (int j = 0; j < 4; ++j)                           \
      bf[j] = *(const bf16x8*)(Bb + boff[j] + (((4 | g) ^ axr) << 3));      \
    if (tt < NT - 2) { asm volatile("s_waitcnt vmcnt(4)" ::: "memory"); }   \
    else             { asm volatile("s_waitcnt vmcnt(0)" ::: "memory"); }   \
    __builtin_amdgcn_s_barrier();                                           \
    asm volatile("s_waitcnt lgkmcnt(0)" ::: "memory");                      \
    __builtin_amdgcn_sched_barrier(0);                                      \
    __builtin_amdgcn_s_setprio(1);                                          \
    _Pragma("unroll") for (int i = 0; i < 4; ++i)                           \
      _Pragma("unroll") for (int j = 0; j < 4; ++j)                         \
        acc[i][j] = mfma_bf16(af[i], bf[j], acc[i][j]);                     \
    __builtin_amdgcn_s_setprio(0);                                          \
    __builtin_amdgcn_s_barrier();                                           \
    sa = (sa == 2) ? 0 : sa + 1;                                            \
  }

// ---------------------------------------------------------------- fused QKV
__global__ __launch_bounds__(512, 1)
void gemm_qkv(const __bf16* __restrict__ A,
              const __bf16* __restrict__ Wqp, const __bf16* __restrict__ Wkp,
              const __bf16* __restrict__ Wvp,
              __bf16* __restrict__ Qo, __bf16* __restrict__ Ko,
              __bf16* __restrict__ Vo,
              const float* __restrict__ fcos, const float* __restrict__ fsin) {
  const int lin = blockIdx.x + blockIdx.y * 24;
  const int bm = (lin & 7) + 8 * ((lin >> 3) / 24);
  const int bn3 = (lin >> 3) % 24;
  const int mode = bn3 >> 3, bn = bn3 & 7;
  const __bf16* W = (mode == 0) ? Wqp : (mode == 1) ? Wkp : Wvp;

  GEMM_PIPELINE

#pragma unroll
  for (int i = 0; i < 4; ++i) {
    const int mbase = bm * 256 + wm * 64 + i * 16 + g * 4;
#pragma unroll
    for (int j = 0; j < 4; ++j) {
      const int col = bn * 128 + wn * 64 + j * 16 + ln;
      if (mode < 2) {
        const int fi = (col & 63) >> 1;
        const bool odd = (col & 1) != 0;
        __bf16* O = (mode == 0) ? Qo : Ko;
        const float sc = (mode == 0) ? 0.1803368802f : 1.0f;
#pragma unroll
        for (int r = 0; r < 4; ++r) {
          const int row = mbase + r;
          const int tok = row & 2047;
          const float cs = fcos[tok * 32 + fi];
          const float sn = fsin[tok * 32 + fi];
          const float own = acc[i][j][r];
          const float oth = __shfl_xor(own, 1);
          O[(size_t)row * 1024 + col] =
              (__bf16)((own * cs + (odd ? oth * sn : -oth * sn)) * sc);
        }
      } else {
        const int bb = mbase >> 11;
        const int tok = mbase & 2047;
        bf16x4 pk;
#pragma unroll
        for (int r = 0; r < 4; ++r) pk[r] = (__bf16)acc[i][j][r];
        *(bf16x4*)(Vo + ((size_t)(bb * 1024 + col)) * 2048 + tok) = pk;
      }
    }
  }
}

// ---------------------------------------------------------------- out GEMM (fp32)
__global__ __launch_bounds__(512, 1)
void gemm_out(const __bf16* __restrict__ A, const __bf16* __restrict__ W,
              float* __restrict__ outp) {
  const int lin = blockIdx.x + blockIdx.y * 8;
  const int bm = (lin & 7) + 8 * ((lin >> 3) & 3);
  const int bn = lin >> 5;

  GEMM_PIPELINE

#pragma unroll
  for (int i = 0; i < 4; ++i) {
    const int mbase = bm * 256 + wm * 64 + i * 16 + g * 4;
#pragma unroll
    for (int j = 0; j < 4; ++j) {
      const int col = bn * 128 + wn * 64 + j * 16 + ln;
#pragma unroll
      for (int r = 0; r < 4; ++r)
        outp[(size_t)(mbase + r) * 1024 + col] = acc[i][j][r];
    }
  }
}

// ---------------------------------------------------------------- flash attention
// Swapped-operand, single 128-row strip per block (UNPAIRED). Grid = 1024
// blocks, longest-first (qt = 15 - lin>>6) so causal imbalance backfills.
// LDS = 50 KB -> 3 blocks/CU (24 waves/CU, +50% TLP vs paired version).
// XCD map: all 16 strips of one bh on one XCD (4 MB KV / XCD = L2 size).
static __device__ __forceinline__ void sm_pack_pv(
    f32x4* sa, float& m, float& l, f32x4* o,
    unsigned int* Pw, const __bf16* Vb, const int g, const int ln) {
  const float a0 = fmaxf(fmaxf(sa[0][0], sa[0][1]), sa[0][2]);
  const float a1 = fmaxf(fmaxf(sa[0][3], sa[1][0]), sa[1][1]);
  const float a2 = fmaxf(fmaxf(sa[1][2], sa[1][3]), sa[2][0]);
  const float a3 = fmaxf(fmaxf(sa[2][1], sa[2][2]), sa[2][3]);
  const float a4 = fmaxf(fmaxf(sa[3][0], sa[3][1]), sa[3][2]);
  float pm = fmaxf(fmaxf(fmaxf(a0, a1), a2), fmaxf(fmaxf(a3, a4), sa[3][3]));

  if (__any(pm > m + 8.f)) {
    pm = fmaxf(pm, __shfl_xor(pm, 16));
    pm = fmaxf(pm, __shfl_xor(pm, 32));
    const float mn = fmaxf(m, pm);
    const float alpha = exp2f(m - mn);
    m = mn;
    l *= alpha;
#pragma unroll
    for (int c2 = 0; c2 < 4; ++c2)
#pragma unroll
      for (int r = 0; r < 4; ++r) o[c2][r] *= alpha;
  }

  float p[4][4];
#pragma unroll
  for (int c = 0; c < 4; ++c)
#pragma unroll
    for (int r = 0; r < 4; ++r) p[c][r] = exp2f(sa[c][r] - m);

  float ts[8];
#pragma unroll
  for (int i = 0; i < 8; ++i) ts[i] = p[i >> 2][i & 3] + p[2 + (i >> 2)][i & 3];
#pragma unroll
  for (int st = 4; st >= 1; st >>= 1)
#pragma unroll
    for (int i = 0; i < st; ++i) ts[i] += ts[i + st];
  float rs = ts[0];
  rs += __shfl_xor(rs, 16);
  rs += __shfl_xor(rs, 32);
  l += rs;

  unsigned int* Pr = Pw + ln * 36;
#pragma unroll
  for (int c = 0; c < 4; ++c) {
    u32x2 w;
    w[0] = cvt_pk_bf16(p[c][0], p[c][1]);
    w[1] = cvt_pk_bf16(p[c][2], p[c][3]);
    *(u32x2*)(Pr + 8 * c + 2 * g) = w;
  }

  __builtin_amdgcn_s_setprio(1);
#pragma unroll
  for (int sh = 0; sh < 2; ++sh) {
    bf16x8 pb = *(const bf16x8*)((const __bf16*)Pw + ln * 72 + sh * 32 + g * 8);
#pragma unroll
    for (int c2 = 0; c2 < 4; ++c2) {
      bf16x8 vf = *(const bf16x8*)(Vb + sh * 2048 + (c2 * 16 + ln) * 32 + g * 8);
      o[c2] = mfma_bf16(vf, pb, o[c2]);
    }
  }
  __builtin_amdgcn_s_setprio(0);
}

__global__ __launch_bounds__(512, 6)
void attn_fwd(const __bf16* __restrict__ Q, const __bf16* __restrict__ Kk,
              const __bf16* __restrict__ Vt, __bf16* __restrict__ U) {
  constexpr int S = 2048;
  __shared__ __align__(16) __bf16 Klds[2][2 * 64 * 32];   // 16 KB
  __shared__ __align__(16) __bf16 Vlds[2][2 * 64 * 32];   // 16 KB
  __shared__ __align__(16) unsigned int Plds[8][16 * 36]; // 18 KB

  const int t = threadIdx.x;
  const int lane = t & 63, wave = t >> 6;
  const int g = lane >> 4, ln = lane & 15;
  const int lin = blockIdx.x + blockIdx.y * 16;
  const int bh = (lin & 7) * 8 + ((lin >> 3) & 7);  // same-bh -> same XCD
  const int qt = 15 - (lin >> 6);                   // longest blocks first
  const int b = bh >> 4, h = bh & 15;
  const int q0 = qt * 128;
  const int nt = 2 * qt + 2;

  // Q fragment: this wave's 16 rows, k-halves 0/1
  const __bf16* Qb = Q + ((size_t)(b * S + q0 + wave * 16 + ln)) * 1024 + h * 64;
  bf16x8 qf0 = *(const bf16x8*)(Qb + g * 8);
  bf16x8 qf1 = *(const bf16x8*)(Qb + 32 + g * 8);

  f32x4 o[4] = {};
  float mrow = -3.0e38f, lrow = 0.f;

  const int half = t >> 8;
  const int srow = (t >> 2) & 63;
  const int scol = (t & 3) * 8;
  const __bf16* Kg = Kk + ((size_t)(b * S + srow)) * 1024 + h * 64 + half * 32 + scol;
  const __bf16* Vg = Vt + ((size_t)(b * 1024 + h * 64 + srow)) * 2048 + half * 32 + scol;

  gload_lds16(Kg, (__bf16*)Klds[0] + t * 8);
  gload_lds16(Vg, (__bf16*)Vlds[0] + t * 8);
  __syncthreads();

  for (int kt = 0; kt < nt; ++kt) {
    const int cur = kt & 1;
    if (kt + 1 < nt) {
      const size_t kv1 = (size_t)(kt + 1) * 64;
      gload_lds16(Kg + kv1 * 1024, (__bf16*)Klds[cur ^ 1] + t * 8);
      gload_lds16(Vg + kv1, (__bf16*)Vlds[cur ^ 1] + t * 8);
    }
    const int kv0 = kt * 64;

    f32x4 sa[4] = {};
    __builtin_amdgcn_s_setprio(1);
#pragma unroll
    for (int s = 0; s < 2; ++s) {
      const bf16x8 qf = s ? qf1 : qf0;
#pragma unroll
      for (int c = 0; c < 4; ++c) {
        bf16x8 kf = *(const bf16x8*)(Klds[cur] + s * 2048 + (c * 16 + ln) * 32 + g * 8);
        sa[c] = mfma_bf16(kf, qf, sa[c]);
      }
    }
    __builtin_amdgcn_s_setprio(0);

    const int rfbase = q0 + wave * 16;
    const int rq = rfbase + ln;
    if (kv0 + 63 > rfbase) {
#pragma unroll
      for (int c = 0; c < 4; ++c)
#pragma unroll
        for (int r = 0; r < 4; ++r)
          if (kv0 + c * 16 + g * 4 + r > rq) sa[c][r] = -1e30f;
    }

    sm_pack_pv(sa, mrow, lrow, o, Plds[wave], Vlds[cur], g, ln);
    __syncthreads();
  }

  const float rl = 1.0f / lrow;
  __bf16* Ub = U + ((size_t)(b * S + q0 + wave * 16 + ln)) * 1024 + h * 64;
#pragma unroll
  for (int c2 = 0; c2 < 4; ++c2) {
    bf16x4 pk4;
#pragma unroll
    for (int r = 0; r < 4; ++r) pk4[r] = (__bf16)(o[c2][r] * rl);
    *(bf16x4*)(Ub + 16 * c2 + 4 * g) = pk4;
  }
}

// ---------------------------------------------------------------- launch
extern "C" void kernel_launch(void* const* d_in, const int* in_sizes, int n_in,
                              void* d_out, int out_size, void* d_ws, size_t ws_size,
                              hipStream_t stream) {
  const float* x    = (const float*)d_in[0];
  const float* fcos = (const float*)d_in[1];
  const float* fsin = (const float*)d_in[2];
  const float* Wq   = (const float*)d_in[3];
  const float* Wk   = (const float*)d_in[4];
  const float* Wv   = (const float*)d_in[5];
  const float* Wo   = (const float*)d_in[6];

  char* ws = (char*)d_ws;
  __bf16* xb  = (__bf16*)(ws);                       // 16 MB
  __bf16* Wqb = (__bf16*)(ws + (16u << 20));         // 2 MB each
  __bf16* Wkb = (__bf16*)(ws + (18u << 20));
  __bf16* Wvb = (__bf16*)(ws + (20u << 20));
  __bf16* Wob = (__bf16*)(ws + (22u << 20));
  __bf16* Qb  = (__bf16*)(ws + (24u << 20));         // 16 MB
  __bf16* Kb  = (__bf16*)(ws + (40u << 20));         // 16 MB
  __bf16* Vtb = (__bf16*)(ws + (56u << 20));         // 16 MB (ends at 72 MB)
  __bf16* Ub  = xb;

  cvt_bf16<<<8192, 256, 0, stream>>>(x, xb, 8192 * 1024 / 4);
  cvt_w4<<<dim3(1024, 4), 256, 0, stream>>>(Wq, Wk, Wv, Wo, Wqb, Wkb, Wvb, Wob);

  const size_t lds = 131072;
  gemm_qkv<<<dim3(24, 32), 512, lds, stream>>>(xb, Wqb, Wkb, Wvb, Qb, Kb, Vtb,
                                               fcos, fsin);
  attn_fwd<<<dim3(16, 64), 512, 0, stream>>>(Qb, Kb, Vtb, Ub);
  gemm_out<<<dim3(8, 32), 512, lds, stream>>>(Ub, Wob, (float*)d_out);
}